// Round 6
// baseline (219.872 us; speedup 1.0000x reference)
//
#include <hip/hip_runtime.h>
#include <stdint.h>
#include <type_traits>

typedef float  v4f  __attribute__((ext_vector_type(4)));
typedef int    v4i  __attribute__((ext_vector_type(4)));
typedef __bf16 v8bf __attribute__((ext_vector_type(8)));
typedef __bf16 v4bf __attribute__((ext_vector_type(4)));

#define BATCH  2
#define NQ     4096
#define MK     1024
#define DMODEL 512
#define DCTX   768
#define NH     8
#define DH     64

// W[K][512] fp32 -> Wt[512][K] bf16; block (0,0,0) also zero-inits scal[0..3]
__global__ __launch_bounds__(256) void k_wtrans(
    const float* __restrict__ Wq, const float* __restrict__ Wk,
    const float* __restrict__ Wv, const float* __restrict__ Wo,
    __bf16* __restrict__ Wq_t, __bf16* __restrict__ Wk_t,
    __bf16* __restrict__ Wv_t, __bf16* __restrict__ Wo_t,
    unsigned* __restrict__ scal) {
  if (blockIdx.x == 0 && blockIdx.y == 0 && blockIdx.z == 0 && threadIdx.x < 4)
    scal[threadIdx.x] = 0u;
  const float* src; __bf16* dst; int K;
  switch (blockIdx.z) {
    case 0:  src = Wq; dst = Wq_t; K = DMODEL; break;
    case 1:  src = Wk; dst = Wk_t; K = DCTX;   break;
    case 2:  src = Wv; dst = Wv_t; K = DCTX;   break;
    default: src = Wo; dst = Wo_t; K = DMODEL; break;
  }
  int k0 = blockIdx.y * 32;
  if (k0 >= K) return;
  int n0 = blockIdx.x * 32;
  __shared__ __bf16 tile[32][33];
  int c = threadIdx.x & 31, r0 = threadIdx.x >> 5;
  for (int i = 0; i < 4; ++i) {
    int r = r0 + i * 8;
    tile[c][r] = (__bf16)src[(size_t)(k0 + r) * DMODEL + n0 + c];
  }
  __syncthreads();
  for (int i = 0; i < 4; ++i) {
    int r = r0 + i * 8;
    dst[(size_t)(n0 + r) * K + k0 + c] = tile[r][c];
  }
}

// C[M][N] = A[M][K] @ Bt[N][K](bf16)^T. Tile MT x 64, BK=64, 4 waves in 2x2:
// each wave (MT/2) x 32. AT = float (cvt in staging) or __bf16 (pure copy).
// Per-element accumulation order identical for all MT -> bit-identical C.
template<int MT, bool BIAS, bool AMAX, typename AT>
__global__ __launch_bounds__(256, 4) void k_gemm(
    const AT* __restrict__ A, const __bf16* __restrict__ Bt,
    float* __restrict__ C, int M, int N, int K,
    const float* __restrict__ bias,
    unsigned* __restrict__ amaxLo, unsigned* __restrict__ amaxHi) {
  constexpr int IT = MT / 32;  // acc row-frags per wave
  __shared__ __bf16 As[MT * 76];
  __shared__ __bf16 Bs[64 * 76];
  __shared__ float redmax[4];
  const int tid = threadIdx.x;
  const int lane = tid & 63, wave = tid >> 6;
  const int l15 = lane & 15, g = lane >> 4;
  const int row0 = blockIdx.x * MT, col0 = blockIdx.y * 64;
  const int wrow = (wave >> 1) * (MT / 2), wcol = (wave & 1) * 32;

  v4f acc[IT][2] = {};

  for (int k0 = 0; k0 < K; k0 += 64) {
    if constexpr (std::is_same<AT, float>::value) {
#pragma unroll
      for (int i = 0; i < MT / 16; ++i) {   // MT x 64 f32 -> bf16
        int f = tid + 256 * i;
        int r = f >> 4, c4 = (f & 15) << 2;
        float4 av = *(const float4*)(A + (size_t)(row0 + r) * K + k0 + c4);
        v4bf ap = { (__bf16)av.x, (__bf16)av.y, (__bf16)av.z, (__bf16)av.w };
        *(v4bf*)(&As[r * 76 + c4]) = ap;
      }
    } else {
#pragma unroll
      for (int i = 0; i < MT / 32; ++i) {   // MT x 64 bf16 copy
        int f = tid + 256 * i;
        int r = f >> 3, c8 = (f & 7) << 3;
        *(v8bf*)(&As[r * 76 + c8]) =
            *(const v8bf*)(A + (size_t)(row0 + r) * K + k0 + c8);
      }
    }
#pragma unroll
    for (int i = 0; i < 2; ++i) {   // B: 64x64 bf16
      int f = tid + 256 * i;
      int r = f >> 3, c8 = (f & 7) << 3;
      *(v8bf*)(&Bs[r * 76 + c8]) =
          *(const v8bf*)(Bt + (size_t)(col0 + r) * K + k0 + c8);
    }
    __syncthreads();
#pragma unroll
    for (int c = 0; c < 2; ++c) {   // two K=32 chunks
      v8bf bf0 = *(const v8bf*)(&Bs[(wcol + l15) * 76 + c * 32 + g * 8]);
      v8bf bf1 = *(const v8bf*)(&Bs[(wcol + 16 + l15) * 76 + c * 32 + g * 8]);
#pragma unroll
      for (int i = 0; i < IT; ++i) {
        v8bf af = *(const v8bf*)(&As[(wrow + i * 16 + l15) * 76 + c * 32 + g * 8]);
        acc[i][0] = __builtin_amdgcn_mfma_f32_16x16x32_bf16(af, bf0, acc[i][0], 0, 0, 0);
        acc[i][1] = __builtin_amdgcn_mfma_f32_16x16x32_bf16(af, bf1, acc[i][1], 0, 0, 0);
      }
    }
    __syncthreads();
  }

  float lmax = 0.0f;
#pragma unroll
  for (int j = 0; j < 2; ++j) {
    int col = col0 + wcol + j * 16 + l15;
    float bv = BIAS ? bias[col] : 0.0f;
#pragma unroll
    for (int i = 0; i < IT; ++i) {
#pragma unroll
      for (int r = 0; r < 4; ++r) {
        int row = row0 + wrow + i * 16 + g * 4 + r;  // C/D: col=lane&15, row=quad*4+reg
        float cv = acc[i][j][r] + bv;
        C[(size_t)row * N + col] = cv;
        if (AMAX) lmax = fmaxf(lmax, fabsf(cv));
      }
    }
  }
  if (AMAX) {
    for (int off = 32; off > 0; off >>= 1)
      lmax = fmaxf(lmax, __shfl_xor(lmax, off, 64));
    if (lane == 0) redmax[wave] = lmax;
    __syncthreads();
    if (tid == 0) {
      float bm = fmaxf(fmaxf(redmax[0], redmax[1]), fmaxf(redmax[2], redmax[3]));
      atomicMax(col0 < 512 ? amaxLo : amaxHi, __float_as_uint(bm));
    }
  }
}

// k/v quantization only (q moved into pass1): blocks [0,1024) quantize k
// (kvf cols 0..511, row stride 1024); [1024,1280) transpose-quantize v
// (kvf cols 512..1023 -> v8t[bh][dh][m]).
__global__ __launch_bounds__(256) void k_quant_kv(
    const float* __restrict__ kvf,
    int8_t* __restrict__ k8, int8_t* __restrict__ v8t,
    const unsigned* __restrict__ scal) {
  __shared__ int8_t tile[64][80];
  int bx = blockIdx.x;
  if (bx < 1024) {
    int j = bx * 256 + threadIdx.x;
    int r = j >> 7;             // 128 float4 per 512-wide k-row
    int c4 = (j & 127) << 2;
    float4 v = *(const float4*)(kvf + (size_t)r * 1024 + c4);
    float s = 127.0f / __uint_as_float(scal[1]);
    int a0 = __float2int_rn(v.x * s), a1 = __float2int_rn(v.y * s);
    int a2 = __float2int_rn(v.z * s), a3 = __float2int_rn(v.w * s);
    a0 = max(-128, min(127, a0)); a1 = max(-128, min(127, a1));
    a2 = max(-128, min(127, a2)); a3 = max(-128, min(127, a3));
    unsigned p = (unsigned)(a0 & 255) | ((unsigned)(a1 & 255) << 8) |
                 ((unsigned)(a2 & 255) << 16) | ((unsigned)(a3 & 255) << 24);
    *(unsigned*)(k8 + (size_t)j * 4) = p;
    return;
  }
  int id = bx - 1024;
  int bh = id >> 4, b = bh >> 3, h = bh & 7;
  int j0 = (id & 15) * 64;
  const float s = 127.0f / __uint_as_float(scal[2]);
  int t = threadIdx.x;
  int j = t >> 2, dh0 = (t & 3) << 4;
  const float* src = kvf + (size_t)(b * MK + j0 + j) * 1024 + 512 + h * DH + dh0;
#pragma unroll
  for (int i = 0; i < 16; i += 4) {
    float4 v = *(const float4*)(src + i);
    int a0 = __float2int_rn(v.x * s), a1 = __float2int_rn(v.y * s);
    int a2 = __float2int_rn(v.z * s), a3 = __float2int_rn(v.w * s);
    tile[dh0 + i + 0][j] = (int8_t)max(-128, min(127, a0));
    tile[dh0 + i + 1][j] = (int8_t)max(-128, min(127, a1));
    tile[dh0 + i + 2][j] = (int8_t)max(-128, min(127, a2));
    tile[dh0 + i + 3][j] = (int8_t)max(-128, min(127, a3));
  }
  __syncthreads();
  int dh = t >> 2, jb = (t & 3) << 4;
  v4i val = *(const v4i*)(&tile[dh][jb]);
  *(v4i*)(v8t + (size_t)(bh * DH + dh) * MK + j0 + jb) = val;
}

__device__ __forceinline__ v4i quant_pack16(const float* p, float s) {
  v4i out;
#pragma unroll
  for (int q = 0; q < 4; ++q) {
    float4 v = *(const float4*)(p + q * 4);
    int a0 = __float2int_rn(v.x * s), a1 = __float2int_rn(v.y * s);
    int a2 = __float2int_rn(v.z * s), a3 = __float2int_rn(v.w * s);
    a0 = max(-128, min(127, a0)); a1 = max(-128, min(127, a1));
    a2 = max(-128, min(127, a2)); a3 = max(-128, min(127, a3));
    out[q] = (int)((unsigned)(a0 & 255) | ((unsigned)(a1 & 255) << 8) |
                   ((unsigned)(a2 & 255) << 16) | ((unsigned)(a3 & 255) << 24));
  }
  return out;
}

// pass 1: quantizes its own q-slice from qf (identical math to the old quant
// kernel -> bit-identical int8), writes q8 for pass2, and uses the packed
// fragment directly. Wave w owns keys [w*256,(w+1)*256); k-quarter in regs.
__global__ __launch_bounds__(256, 4) void k_pass1(
    const float* __restrict__ qf, int8_t* __restrict__ q8,
    const int8_t* __restrict__ k8,
    float* __restrict__ invz, unsigned* __restrict__ scal) {
  __shared__ float zbuf[4][64];
  __shared__ int   mbuf[4][64];
  int bh = blockIdx.y, b = bh >> 3, h = bh & 7;
  int wave = threadIdx.x >> 6, lane = threadIdx.x & 63;
  int l15 = lane & 15, g = lane >> 4;
  int row0 = blockIdx.x * 64;
  const float aq = __uint_as_float(scal[0]), ak = __uint_as_float(scal[1]);
  const float alpha2 = (aq * ak) * (0.125f / (127.0f * 127.0f)) * 1.44269504f;
  const float sq = 127.0f / aq;
  const v4i z4 = {0, 0, 0, 0};
  v4i qfrag[4];
#pragma unroll
  for (int rg = 0; rg < 4; ++rg) {
    size_t off = (size_t)(b * NQ + row0 + rg * 16 + l15) * DMODEL + h * DH + g * 16;
    qfrag[rg] = quant_pack16(qf + off, sq);
    *(v4i*)(q8 + off) = qfrag[rg];
  }
  const int8_t* kbase = k8 + (size_t)b * MK * DMODEL + h * DH + g * 16 +
                        (size_t)wave * 256 * DMODEL;
  v4i kf[16];
#pragma unroll
  for (int i = 0; i < 16; ++i)
    kf[i] = *(const v4i*)(kbase + (size_t)(i * 16 + l15) * DMODEL);

  float z[4] = {0.f, 0.f, 0.f, 0.f};
  int mi[4] = {-(1 << 30), -(1 << 30), -(1 << 30), -(1 << 30)};
#pragma unroll
  for (int kt = 0; kt < 16; ++kt) {
#pragma unroll
    for (int rg = 0; rg < 4; ++rg) {
      v4i sa = __builtin_amdgcn_mfma_i32_16x16x64_i8(kf[kt], qfrag[rg], z4, 0, 0, 0);
      mi[rg] = max(mi[rg], max(max(sa[0], sa[1]), max(sa[2], sa[3])));
      float e0 = __builtin_amdgcn_exp2f((float)sa[0] * alpha2);
      float e1 = __builtin_amdgcn_exp2f((float)sa[1] * alpha2);
      float e2 = __builtin_amdgcn_exp2f((float)sa[2] * alpha2);
      float e3 = __builtin_amdgcn_exp2f((float)sa[3] * alpha2);
      z[rg] += (e0 + e1) + (e2 + e3);
    }
  }
#pragma unroll
  for (int rg = 0; rg < 4; ++rg) {
    z[rg] += __shfl_xor(z[rg], 16, 64);
    mi[rg] = max(mi[rg], __shfl_xor(mi[rg], 16, 64));
    z[rg] += __shfl_xor(z[rg], 32, 64);
    mi[rg] = max(mi[rg], __shfl_xor(mi[rg], 32, 64));
  }
  if (lane < 16) {
#pragma unroll
    for (int rg = 0; rg < 4; ++rg) {
      zbuf[wave][rg * 16 + l15] = z[rg];
      mbuf[wave][rg * 16 + l15] = mi[rg];
    }
  }
  __syncthreads();
  if (threadIdx.x < 64) {
    int r = threadIdx.x;
    float zt = (zbuf[0][r] + zbuf[1][r]) + (zbuf[2][r] + zbuf[3][r]);
    int mt = max(max(mbuf[0][r], mbuf[1][r]), max(mbuf[2][r], mbuf[3][r]));
    float iz = 1.0f / zt;
    invz[(size_t)bh * NQ + row0 + r] = iz;
    float ma = __builtin_amdgcn_exp2f((float)mt * alpha2) * iz;  // row softmax max
    for (int off = 1; off < 64; off <<= 1)
      ma = fmaxf(ma, __shfl_xor(ma, off, 64));
    if (r == 0) atomicMax(scal + 3, __float_as_uint(ma));
  }
}

// pass 2: register-resident k/v quarters; per-rg cross-wave reduction; stores
// o in bf16 (same RNE conversion the out-GEMM staging used to do -> identical).
__global__ __launch_bounds__(256, 2) void k_pass2(
    const int8_t* __restrict__ q8, const int8_t* __restrict__ k8,
    const int8_t* __restrict__ v8t, const float* __restrict__ invz,
    const unsigned* __restrict__ scal, __bf16* __restrict__ o) {
  __shared__ __align__(16) int8_t attn_lds[4][16 * 80];  // 5 KB, wave-private
  __shared__ __align__(16) int redbuf[16][64][4];        // 16 KB cross-wave reduce
  int bh = blockIdx.y, b = bh >> 3, h = bh & 7;
  int wave = threadIdx.x >> 6, lane = threadIdx.x & 63;
  int l15 = lane & 15, g = lane >> 4;
  int row0 = blockIdx.x * 64;
  int key0 = wave * 256;
  const float aq = __uint_as_float(scal[0]), ak = __uint_as_float(scal[1]);
  const float avv = __uint_as_float(scal[2]), izm = __uint_as_float(scal[3]);
  const float alpha2 = (aq * ak) * (0.125f / (127.0f * 127.0f)) * 1.44269504f;
  const float oscale = (izm / 127.0f) * (avv / 127.0f);  // delta_attn * delta_v
  const float MAGIC = 12582912.0f;                       // 1.5 * 2^23
  const v4i z4 = {0, 0, 0, 0};

  v4i qfrag[4];
  float lc[4];
#pragma unroll
  for (int rg = 0; rg < 4; ++rg) {
    qfrag[rg] = *(const v4i*)(q8 + (size_t)(b * NQ + row0 + rg * 16 + l15) * DMODEL + h * DH + g * 16);
    lc[rg] = __builtin_amdgcn_logf(invz[(size_t)bh * NQ + row0 + rg * 16 + l15] * (127.0f / izm));
  }
  const int8_t* kbase = k8 + (size_t)(b * MK + key0) * DMODEL + h * DH + g * 16;
  v4i kf[16];
#pragma unroll
  for (int i = 0; i < 16; ++i)
    kf[i] = *(const v4i*)(kbase + (size_t)(i * 16 + l15) * DMODEL);
  const int8_t* vbase = v8t + (size_t)bh * DH * MK + key0 + g * 16;
  v4i vf[16];
#pragma unroll
  for (int d = 0; d < 4; ++d)
#pragma unroll
    for (int c = 0; c < 4; ++c)
      vf[d * 4 + c] = *(const v4i*)(vbase + (size_t)(d * 16 + l15) * MK + c * 64);

  int8_t* alds = attn_lds[wave];
  __bf16* obase = o + (size_t)(b * NQ + row0) * DMODEL + h * DH;

#pragma unroll
  for (int rg = 0; rg < 4; ++rg) {
    const float lcr = lc[rg];
    v4i pacc[4] = {};
#pragma unroll
    for (int c = 0; c < 4; ++c) {
#pragma unroll
      for (int t = 0; t < 4; ++t) {
        v4i sa = __builtin_amdgcn_mfma_i32_16x16x64_i8(kf[c * 4 + t], qfrag[rg], z4, 0, 0, 0);
        float f0 = __builtin_amdgcn_exp2f(fmaf((float)sa[0], alpha2, lcr)) + MAGIC;
        float f1 = __builtin_amdgcn_exp2f(fmaf((float)sa[1], alpha2, lcr)) + MAGIC;
        float f2 = __builtin_amdgcn_exp2f(fmaf((float)sa[2], alpha2, lcr)) + MAGIC;
        float f3 = __builtin_amdgcn_exp2f(fmaf((float)sa[3], alpha2, lcr)) + MAGIC;
        unsigned packed = (__float_as_uint(f0) & 255u) |
                          ((__float_as_uint(f1) & 255u) << 8) |
                          ((__float_as_uint(f2) & 255u) << 16) |
                          (__float_as_uint(f3) << 24);
        // C-layout: col(l15)=q-row, row(g*4+r)=key -> store at [qrow][key_local]
        *(unsigned*)(alds + l15 * 80 + t * 16 + g * 4) = packed;
      }
      // wave-private LDS; DS pipe in-order per wave -> no barrier
      v4i afrag = *(const v4i*)(alds + l15 * 80 + g * 16);  // A-layout read
#pragma unroll
      for (int d = 0; d < 4; ++d)
        pacc[d] = __builtin_amdgcn_mfma_i32_16x16x64_i8(afrag, vf[d * 4 + c], pacc[d], 0, 0, 0);
    }
    __syncthreads();
#pragma unroll
    for (int d = 0; d < 4; ++d)
      *(v4i*)(&redbuf[wave * 4 + d][lane][0]) = pacc[d];
    __syncthreads();
    v4i s0 = *(const v4i*)(&redbuf[wave][lane][0]);
    v4i s1 = *(const v4i*)(&redbuf[4 + wave][lane][0]);
    v4i s2 = *(const v4i*)(&redbuf[8 + wave][lane][0]);
    v4i s3 = *(const v4i*)(&redbuf[12 + wave][lane][0]);
    v4i sum = (s0 + s1) + (s2 + s3);
#pragma unroll
    for (int r = 0; r < 4; ++r) {
      int row = rg * 16 + (lane >> 4) * 4 + r;
      obase[(size_t)row * DMODEL + wave * 16 + (lane & 15)] =
          (__bf16)((float)sum[r] * oscale);
    }
  }
}

extern "C" void kernel_launch(void* const* d_in, const int* in_sizes, int n_in,
                              void* d_out, int out_size, void* d_ws, size_t ws_size,
                              hipStream_t stream) {
  (void)in_sizes; (void)n_in; (void)out_size; (void)ws_size;
  const float* x   = (const float*)d_in[0];
  const float* ctx = (const float*)d_in[1];
  const float* Wq  = (const float*)d_in[2];
  const float* Wk  = (const float*)d_in[3];
  const float* Wv  = (const float*)d_in[4];
  const float* Wo  = (const float*)d_in[5];
  const float* bo  = (const float*)d_in[6];
  float* out = (float*)d_out;

  char* ws = (char*)d_ws;
  size_t off = 0;
  auto alloc = [&](size_t bytes) {
    char* p = ws + off;
    off += (bytes + 255) & ~(size_t)255;
    return p;
  };
  unsigned* scal = (unsigned*)alloc(16);
  __bf16* Wq_t = (__bf16*)alloc((size_t)512 * 512 * 2);
  __bf16* Wk_t = (__bf16*)alloc((size_t)512 * 768 * 2);  // contiguous with Wv_t:
  __bf16* Wv_t = (__bf16*)alloc((size_t)512 * 768 * 2);  //   B for fused kv GEMM (N=1024)
  __bf16* Wo_t = (__bf16*)alloc((size_t)512 * 512 * 2);
  float* qf  = (float*)alloc((size_t)BATCH * NQ * DMODEL * 4);   // later reused as o
  float* kvf = (float*)alloc((size_t)BATCH * MK * 1024 * 4);     // [2048][1024]: k | v
  int8_t* q8 = (int8_t*)alloc((size_t)BATCH * NQ * DMODEL);
  int8_t* k8 = (int8_t*)alloc((size_t)BATCH * MK * DMODEL);
  int8_t* v8t = (int8_t*)alloc((size_t)BATCH * NH * DH * MK);
  float* invz = (float*)alloc((size_t)BATCH * NH * NQ * 4);
  __bf16* o = (__bf16*)qf;  // q_f32 dead after pass1 quantizes it

  k_wtrans<<<dim3(16, 24, 4), 256, 0, stream>>>(Wq, Wk, Wv, Wo, Wq_t, Wk_t, Wv_t, Wo_t, scal);
  k_gemm<128, false, true, float><<<dim3(64, 8), 256, 0, stream>>>(
      x, Wq_t, qf, 8192, 512, 512, nullptr, scal + 0, scal + 0);
  k_gemm<64, false, true, float><<<dim3(32, 16), 256, 0, stream>>>(
      ctx, Wk_t, kvf, 2048, 1024, 768, nullptr, scal + 1, scal + 2);
  k_quant_kv<<<1280, 256, 0, stream>>>(kvf, k8, v8t, scal);
  k_pass1<<<dim3(64, 16), 256, 0, stream>>>(qf, q8, k8, invz, scal);
  k_pass2<<<dim3(64, 16), 256, 0, stream>>>(q8, k8, v8t, invz, scal, o);
  k_gemm<128, true, false, __bf16><<<dim3(64, 8), 256, 0, stream>>>(
      o, Wo_t, out, 8192, 512, 512, bo, nullptr, nullptr);
}

// Round 7
// 204.337 us; speedup vs baseline: 1.0760x; 1.0760x over previous
//
#include <hip/hip_runtime.h>
#include <stdint.h>

typedef float  v4f  __attribute__((ext_vector_type(4)));
typedef int    v4i  __attribute__((ext_vector_type(4)));
typedef __bf16 v8bf __attribute__((ext_vector_type(8)));
typedef __bf16 v4bf __attribute__((ext_vector_type(4)));

#define BATCH  2
#define NQ     4096
#define MK     1024
#define DMODEL 512
#define DCTX   768
#define NH     8
#define DH     64

// W[K][512] fp32 -> Wt[512][K] bf16; block (0,0,0) also zero-inits scal[0..3]
__global__ __launch_bounds__(256) void k_wtrans(
    const float* __restrict__ Wq, const float* __restrict__ Wk,
    const float* __restrict__ Wv, const float* __restrict__ Wo,
    __bf16* __restrict__ Wq_t, __bf16* __restrict__ Wk_t,
    __bf16* __restrict__ Wv_t, __bf16* __restrict__ Wo_t,
    unsigned* __restrict__ scal) {
  if (blockIdx.x == 0 && blockIdx.y == 0 && blockIdx.z == 0 && threadIdx.x < 4)
    scal[threadIdx.x] = 0u;
  const float* src; __bf16* dst; int K;
  switch (blockIdx.z) {
    case 0:  src = Wq; dst = Wq_t; K = DMODEL; break;
    case 1:  src = Wk; dst = Wk_t; K = DCTX;   break;
    case 2:  src = Wv; dst = Wv_t; K = DCTX;   break;
    default: src = Wo; dst = Wo_t; K = DMODEL; break;
  }
  int k0 = blockIdx.y * 32;
  if (k0 >= K) return;
  int n0 = blockIdx.x * 32;
  __shared__ __bf16 tile[32][33];
  int c = threadIdx.x & 31, r0 = threadIdx.x >> 5;
  for (int i = 0; i < 4; ++i) {
    int r = r0 + i * 8;
    tile[c][r] = (__bf16)src[(size_t)(k0 + r) * DMODEL + n0 + c];
  }
  __syncthreads();
  for (int i = 0; i < 4; ++i) {
    int r = r0 + i * 8;
    dst[(size_t)(n0 + r) * K + k0 + c] = tile[r][c];
  }
}

// x (4.19M elems) and ctx (1.57M elems) fp32 -> bf16 (same RNE cvt the old GEMM
// staging applied per-tile -> downstream bits identical).
__global__ __launch_bounds__(256) void k_cvt(
    const float* __restrict__ x, const float* __restrict__ ctx,
    __bf16* __restrict__ xb, __bf16* __restrict__ cb) {
  const int XC = BATCH * NQ * DMODEL / 8;   // 524288 v8 chunks
  const int CC = BATCH * MK * DCTX / 8;     // 196608
  int idx = blockIdx.x * 256 + threadIdx.x;
  const float* src; __bf16* dst;
  if (idx < XC) { src = x + (size_t)idx * 8; dst = xb + (size_t)idx * 8; }
  else {
    int j = idx - XC;
    if (j >= CC) return;
    src = ctx + (size_t)j * 8; dst = cb + (size_t)j * 8;
  }
  float4 a = *(const float4*)src, b = *(const float4*)(src + 4);
  v8bf o = { (__bf16)a.x, (__bf16)a.y, (__bf16)a.z, (__bf16)a.w,
             (__bf16)b.x, (__bf16)b.y, (__bf16)b.z, (__bf16)b.w };
  *(v8bf*)dst = o;
}

// B-stationary GEMM: C[M][N] = A[M][K](bf16) @ Bt[N][K](bf16)^T.
// Block: 128 rows x 32 cols; the 32-col B panel for ALL of K lives in LDS
// (staged once, one barrier, +8-elem pad per col -> 2-way banks = free).
// K-loop is barrier-free: per iter 2 gmem A-loads + 2 ds_read_b128 + 4 MFMA.
// MFMA order per element: k ascending, 16x16x32 -> bit-identical to before.
template<int K_, bool BIAS, bool AMAX>
__global__ __launch_bounds__(256, 3) void k_gemm_bs(
    const __bf16* __restrict__ A, const __bf16* __restrict__ Bt,
    float* __restrict__ C, int M, int N,
    const float* __restrict__ bias,
    unsigned* __restrict__ amaxLo, unsigned* __restrict__ amaxHi) {
  constexpr int CS = K_ + 8;            // col stride (elems): pad 16 B
  constexpr int GPC = K_ / 8;           // 16B granules per col (64 or 96)
  __shared__ __bf16 Bs[32 * CS];
  __shared__ float redmax[4];
  const int tid = threadIdx.x;
  const int lane = tid & 63, wave = tid >> 6;
  const int l15 = lane & 15, g = lane >> 4;
  const int col0 = blockIdx.y * 32;
  const int row0w = blockIdx.x * 128 + wave * 32;

  // stage B panel: gmem reads fully coalesced (granule-linear over the panel)
#pragma unroll
  for (int i = 0; i < GPC * 32 / 256; ++i) {
    int f = i * 256 + tid;              // granule index in panel
    int c = f / GPC, w = f - c * GPC;
    *(v8bf*)(&Bs[c * CS + w * 8]) =
        *(const v8bf*)(Bt + (size_t)(col0 + c) * K_ + w * 8);
  }
  __syncthreads();

  v4f acc[2][2] = {};
  const __bf16* a0 = A + (size_t)(row0w + l15) * K_ + g * 8;
  const __bf16* a1 = A + (size_t)(row0w + 16 + l15) * K_ + g * 8;
#pragma unroll
  for (int k0 = 0; k0 < K_; k0 += 32) {
    v8bf af0 = *(const v8bf*)(a0 + k0);
    v8bf af1 = *(const v8bf*)(a1 + k0);
    v8bf bf0 = *(const v8bf*)(&Bs[l15 * CS + k0 + g * 8]);
    v8bf bf1 = *(const v8bf*)(&Bs[(16 + l15) * CS + k0 + g * 8]);
    acc[0][0] = __builtin_amdgcn_mfma_f32_16x16x32_bf16(af0, bf0, acc[0][0], 0, 0, 0);
    acc[0][1] = __builtin_amdgcn_mfma_f32_16x16x32_bf16(af0, bf1, acc[0][1], 0, 0, 0);
    acc[1][0] = __builtin_amdgcn_mfma_f32_16x16x32_bf16(af1, bf0, acc[1][0], 0, 0, 0);
    acc[1][1] = __builtin_amdgcn_mfma_f32_16x16x32_bf16(af1, bf1, acc[1][1], 0, 0, 0);
  }

  float lmax = 0.0f;
#pragma unroll
  for (int j = 0; j < 2; ++j) {
    int col = col0 + j * 16 + l15;
    float bv = BIAS ? bias[col] : 0.0f;
#pragma unroll
    for (int i = 0; i < 2; ++i) {
#pragma unroll
      for (int r = 0; r < 4; ++r) {
        int row = row0w + i * 16 + g * 4 + r;  // C/D: col=lane&15, row=quad*4+reg
        float cv = acc[i][j][r] + bv;
        C[(size_t)row * N + col] = cv;
        if (AMAX) lmax = fmaxf(lmax, fabsf(cv));
      }
    }
  }
  if (AMAX) {
    for (int off = 32; off > 0; off >>= 1)
      lmax = fmaxf(lmax, __shfl_xor(lmax, off, 64));
    if (lane == 0) redmax[wave] = lmax;
    __syncthreads();
    if (tid == 0) {
      float bm = fmaxf(fmaxf(redmax[0], redmax[1]), fmaxf(redmax[2], redmax[3]));
      atomicMax(col0 < 512 ? amaxLo : amaxHi, __float_as_uint(bm));
    }
  }
}

// k/v quantization: blocks [0,1024) quantize k (kvf cols 0..511, row stride
// 1024); [1024,1280) transpose-quantize v (kvf cols 512..1023 -> v8t[bh][dh][m]).
__global__ __launch_bounds__(256) void k_quant_kv(
    const float* __restrict__ kvf,
    int8_t* __restrict__ k8, int8_t* __restrict__ v8t,
    const unsigned* __restrict__ scal) {
  __shared__ int8_t tile[64][80];
  int bx = blockIdx.x;
  if (bx < 1024) {
    int j = bx * 256 + threadIdx.x;
    int r = j >> 7;
    int c4 = (j & 127) << 2;
    float4 v = *(const float4*)(kvf + (size_t)r * 1024 + c4);
    float s = 127.0f / __uint_as_float(scal[1]);
    int a0 = __float2int_rn(v.x * s), a1 = __float2int_rn(v.y * s);
    int a2 = __float2int_rn(v.z * s), a3 = __float2int_rn(v.w * s);
    a0 = max(-128, min(127, a0)); a1 = max(-128, min(127, a1));
    a2 = max(-128, min(127, a2)); a3 = max(-128, min(127, a3));
    unsigned p = (unsigned)(a0 & 255) | ((unsigned)(a1 & 255) << 8) |
                 ((unsigned)(a2 & 255) << 16) | ((unsigned)(a3 & 255) << 24);
    *(unsigned*)(k8 + (size_t)j * 4) = p;
    return;
  }
  int id = bx - 1024;
  int bh = id >> 4, b = bh >> 3, h = bh & 7;
  int j0 = (id & 15) * 64;
  const float s = 127.0f / __uint_as_float(scal[2]);
  int t = threadIdx.x;
  int j = t >> 2, dh0 = (t & 3) << 4;
  const float* src = kvf + (size_t)(b * MK + j0 + j) * 1024 + 512 + h * DH + dh0;
#pragma unroll
  for (int i = 0; i < 16; i += 4) {
    float4 v = *(const float4*)(src + i);
    int a0 = __float2int_rn(v.x * s), a1 = __float2int_rn(v.y * s);
    int a2 = __float2int_rn(v.z * s), a3 = __float2int_rn(v.w * s);
    tile[dh0 + i + 0][j] = (int8_t)max(-128, min(127, a0));
    tile[dh0 + i + 1][j] = (int8_t)max(-128, min(127, a1));
    tile[dh0 + i + 2][j] = (int8_t)max(-128, min(127, a2));
    tile[dh0 + i + 3][j] = (int8_t)max(-128, min(127, a3));
  }
  __syncthreads();
  int dh = t >> 2, jb = (t & 3) << 4;
  v4i val = *(const v4i*)(&tile[dh][jb]);
  *(v4i*)(v8t + (size_t)(bh * DH + dh) * MK + j0 + jb) = val;
}

__device__ __forceinline__ v4i quant_pack16(const float* p, float s) {
  v4i out;
#pragma unroll
  for (int q = 0; q < 4; ++q) {
    float4 v = *(const float4*)(p + q * 4);
    int a0 = __float2int_rn(v.x * s), a1 = __float2int_rn(v.y * s);
    int a2 = __float2int_rn(v.z * s), a3 = __float2int_rn(v.w * s);
    a0 = max(-128, min(127, a0)); a1 = max(-128, min(127, a1));
    a2 = max(-128, min(127, a2)); a3 = max(-128, min(127, a3));
    out[q] = (int)((unsigned)(a0 & 255) | ((unsigned)(a1 & 255) << 8) |
                   ((unsigned)(a2 & 255) << 16) | ((unsigned)(a3 & 255) << 24));
  }
  return out;
}

// pass 1: quantizes its own q-slice from qf (bit-identical math), writes q8,
// uses the packed fragment directly. Wave w owns keys [w*256,(w+1)*256).
__global__ __launch_bounds__(256, 4) void k_pass1(
    const float* __restrict__ qf, int8_t* __restrict__ q8,
    const int8_t* __restrict__ k8,
    float* __restrict__ invz, unsigned* __restrict__ scal) {
  __shared__ float zbuf[4][64];
  __shared__ int   mbuf[4][64];
  int bh = blockIdx.y, b = bh >> 3, h = bh & 7;
  int wave = threadIdx.x >> 6, lane = threadIdx.x & 63;
  int l15 = lane & 15, g = lane >> 4;
  int row0 = blockIdx.x * 64;
  const float aq = __uint_as_float(scal[0]), ak = __uint_as_float(scal[1]);
  const float alpha2 = (aq * ak) * (0.125f / (127.0f * 127.0f)) * 1.44269504f;
  const float sq = 127.0f / aq;
  const v4i z4 = {0, 0, 0, 0};
  v4i qfrag[4];
#pragma unroll
  for (int rg = 0; rg < 4; ++rg) {
    size_t off = (size_t)(b * NQ + row0 + rg * 16 + l15) * DMODEL + h * DH + g * 16;
    qfrag[rg] = quant_pack16(qf + off, sq);
    *(v4i*)(q8 + off) = qfrag[rg];
  }
  const int8_t* kbase = k8 + (size_t)b * MK * DMODEL + h * DH + g * 16 +
                        (size_t)wave * 256 * DMODEL;
  v4i kf[16];
#pragma unroll
  for (int i = 0; i < 16; ++i)
    kf[i] = *(const v4i*)(kbase + (size_t)(i * 16 + l15) * DMODEL);

  float z[4] = {0.f, 0.f, 0.f, 0.f};
  int mi[4] = {-(1 << 30), -(1 << 30), -(1 << 30), -(1 << 30)};
#pragma unroll
  for (int kt = 0; kt < 16; ++kt) {
#pragma unroll
    for (int rg = 0; rg < 4; ++rg) {
      v4i sa = __builtin_amdgcn_mfma_i32_16x16x64_i8(kf[kt], qfrag[rg], z4, 0, 0, 0);
      mi[rg] = max(mi[rg], max(max(sa[0], sa[1]), max(sa[2], sa[3])));
      float e0 = __builtin_amdgcn_exp2f((float)sa[0] * alpha2);
      float e1 = __builtin_amdgcn_exp2f((float)sa[1] * alpha2);
      float e2 = __builtin_amdgcn_exp2f((float)sa[2] * alpha2);
      float e3 = __builtin_amdgcn_exp2f((float)sa[3] * alpha2);
      z[rg] += (e0 + e1) + (e2 + e3);
    }
  }
#pragma unroll
  for (int rg = 0; rg < 4; ++rg) {
    z[rg] += __shfl_xor(z[rg], 16, 64);
    mi[rg] = max(mi[rg], __shfl_xor(mi[rg], 16, 64));
    z[rg] += __shfl_xor(z[rg], 32, 64);
    mi[rg] = max(mi[rg], __shfl_xor(mi[rg], 32, 64));
  }
  if (lane < 16) {
#pragma unroll
    for (int rg = 0; rg < 4; ++rg) {
      zbuf[wave][rg * 16 + l15] = z[rg];
      mbuf[wave][rg * 16 + l15] = mi[rg];
    }
  }
  __syncthreads();
  if (threadIdx.x < 64) {
    int r = threadIdx.x;
    float zt = (zbuf[0][r] + zbuf[1][r]) + (zbuf[2][r] + zbuf[3][r]);
    int mt = max(max(mbuf[0][r], mbuf[1][r]), max(mbuf[2][r], mbuf[3][r]));
    float iz = 1.0f / zt;
    invz[(size_t)bh * NQ + row0 + r] = iz;
    float ma = __builtin_amdgcn_exp2f((float)mt * alpha2) * iz;  // row softmax max
    for (int off = 1; off < 64; off <<= 1)
      ma = fmaxf(ma, __shfl_xor(ma, off, 64));
    if (r == 0) atomicMax(scal + 3, __float_as_uint(ma));
  }
}

// pass 2: register-resident k/v quarters; per-rg cross-wave reduction; stores
// o in bf16 (same RNE conversion the out-GEMM staging used to do).
__global__ __launch_bounds__(256, 2) void k_pass2(
    const int8_t* __restrict__ q8, const int8_t* __restrict__ k8,
    const int8_t* __restrict__ v8t, const float* __restrict__ invz,
    const unsigned* __restrict__ scal, __bf16* __restrict__ o) {
  __shared__ __align__(16) int8_t attn_lds[4][16 * 80];  // 5 KB, wave-private
  __shared__ __align__(16) int redbuf[16][64][4];        // 16 KB cross-wave reduce
  int bh = blockIdx.y, b = bh >> 3, h = bh & 7;
  int wave = threadIdx.x >> 6, lane = threadIdx.x & 63;
  int l15 = lane & 15, g = lane >> 4;
  int row0 = blockIdx.x * 64;
  int key0 = wave * 256;
  const float aq = __uint_as_float(scal[0]), ak = __uint_as_float(scal[1]);
  const float avv = __uint_as_float(scal[2]), izm = __uint_as_float(scal[3]);
  const float alpha2 = (aq * ak) * (0.125f / (127.0f * 127.0f)) * 1.44269504f;
  const float oscale = (izm / 127.0f) * (avv / 127.0f);  // delta_attn * delta_v
  const float MAGIC = 12582912.0f;                       // 1.5 * 2^23
  const v4i z4 = {0, 0, 0, 0};

  v4i qfrag[4];
  float lc[4];
#pragma unroll
  for (int rg = 0; rg < 4; ++rg) {
    qfrag[rg] = *(const v4i*)(q8 + (size_t)(b * NQ + row0 + rg * 16 + l15) * DMODEL + h * DH + g * 16);
    lc[rg] = __builtin_amdgcn_logf(invz[(size_t)bh * NQ + row0 + rg * 16 + l15] * (127.0f / izm));
  }
  const int8_t* kbase = k8 + (size_t)(b * MK + key0) * DMODEL + h * DH + g * 16;
  v4i kf[16];
#pragma unroll
  for (int i = 0; i < 16; ++i)
    kf[i] = *(const v4i*)(kbase + (size_t)(i * 16 + l15) * DMODEL);
  const int8_t* vbase = v8t + (size_t)bh * DH * MK + key0 + g * 16;
  v4i vf[16];
#pragma unroll
  for (int d = 0; d < 4; ++d)
#pragma unroll
    for (int c = 0; c < 4; ++c)
      vf[d * 4 + c] = *(const v4i*)(vbase + (size_t)(d * 16 + l15) * MK + c * 64);

  int8_t* alds = attn_lds[wave];
  __bf16* obase = o + (size_t)(b * NQ + row0) * DMODEL + h * DH;

#pragma unroll
  for (int rg = 0; rg < 4; ++rg) {
    const float lcr = lc[rg];
    v4i pacc[4] = {};
#pragma unroll
    for (int c = 0; c < 4; ++c) {
#pragma unroll
      for (int t = 0; t < 4; ++t) {
        v4i sa = __builtin_amdgcn_mfma_i32_16x16x64_i8(kf[c * 4 + t], qfrag[rg], z4, 0, 0, 0);
        float f0 = __builtin_amdgcn_exp2f(fmaf((float)sa[0], alpha2, lcr)) + MAGIC;
        float f1 = __builtin_amdgcn_exp2f(fmaf((float)sa[1], alpha2, lcr)) + MAGIC;
        float f2 = __builtin_amdgcn_exp2f(fmaf((float)sa[2], alpha2, lcr)) + MAGIC;
        float f3 = __builtin_amdgcn_exp2f(fmaf((float)sa[3], alpha2, lcr)) + MAGIC;
        unsigned packed = (__float_as_uint(f0) & 255u) |
                          ((__float_as_uint(f1) & 255u) << 8) |
                          ((__float_as_uint(f2) & 255u) << 16) |
                          (__float_as_uint(f3) << 24);
        *(unsigned*)(alds + l15 * 80 + t * 16 + g * 4) = packed;
      }
      v4i afrag = *(const v4i*)(alds + l15 * 80 + g * 16);  // A-layout read
#pragma unroll
      for (int d = 0; d < 4; ++d)
        pacc[d] = __builtin_amdgcn_mfma_i32_16x16x64_i8(afrag, vf[d * 4 + c], pacc[d], 0, 0, 0);
    }
    __syncthreads();
#pragma unroll
    for (int d = 0; d < 4; ++d)
      *(v4i*)(&redbuf[wave * 4 + d][lane][0]) = pacc[d];
    __syncthreads();
    v4i s0 = *(const v4i*)(&redbuf[wave][lane][0]);
    v4i s1 = *(const v4i*)(&redbuf[4 + wave][lane][0]);
    v4i s2 = *(const v4i*)(&redbuf[8 + wave][lane][0]);
    v4i s3 = *(const v4i*)(&redbuf[12 + wave][lane][0]);
    v4i sum = (s0 + s1) + (s2 + s3);
#pragma unroll
    for (int r = 0; r < 4; ++r) {
      int row = rg * 16 + (lane >> 4) * 4 + r;
      obase[(size_t)row * DMODEL + wave * 16 + (lane & 15)] =
          (__bf16)((float)sum[r] * oscale);
    }
  }
}

extern "C" void kernel_launch(void* const* d_in, const int* in_sizes, int n_in,
                              void* d_out, int out_size, void* d_ws, size_t ws_size,
                              hipStream_t stream) {
  (void)in_sizes; (void)n_in; (void)out_size; (void)ws_size;
  const float* x   = (const float*)d_in[0];
  const float* ctx = (const float*)d_in[1];
  const float* Wq  = (const float*)d_in[2];
  const float* Wk  = (const float*)d_in[3];
  const float* Wv  = (const float*)d_in[4];
  const float* Wo  = (const float*)d_in[5];
  const float* bo  = (const float*)d_in[6];
  float* out = (float*)d_out;

  char* ws = (char*)d_ws;
  size_t off = 0;
  auto alloc = [&](size_t bytes) {
    char* p = ws + off;
    off += (bytes + 255) & ~(size_t)255;
    return p;
  };
  unsigned* scal = (unsigned*)alloc(16);
  __bf16* Wq_t = (__bf16*)alloc((size_t)512 * 512 * 2);
  __bf16* Wk_t = (__bf16*)alloc((size_t)512 * 768 * 2);  // contiguous with Wv_t
  __bf16* Wv_t = (__bf16*)alloc((size_t)512 * 768 * 2);
  __bf16* Wo_t = (__bf16*)alloc((size_t)512 * 512 * 2);
  __bf16* xb   = (__bf16*)alloc((size_t)BATCH * NQ * DMODEL * 2);
  __bf16* cb   = (__bf16*)alloc((size_t)BATCH * MK * DCTX * 2);
  float* qf  = (float*)alloc((size_t)BATCH * NQ * DMODEL * 4);   // later reused as o
  float* kvf = (float*)alloc((size_t)BATCH * MK * 1024 * 4);     // [2048][1024]: k | v
  int8_t* q8 = (int8_t*)alloc((size_t)BATCH * NQ * DMODEL);
  int8_t* k8 = (int8_t*)alloc((size_t)BATCH * MK * DMODEL);
  int8_t* v8t = (int8_t*)alloc((size_t)BATCH * NH * DH * MK);
  float* invz = (float*)alloc((size_t)BATCH * NH * NQ * 4);
  __bf16* o = (__bf16*)qf;  // q_f32 dead after pass1 quantizes it

  k_wtrans<<<dim3(16, 24, 4), 256, 0, stream>>>(Wq, Wk, Wv, Wo, Wq_t, Wk_t, Wv_t, Wo_t, scal);
  k_cvt<<<2816, 256, 0, stream>>>(x, ctx, xb, cb);
  k_gemm_bs<512, false, true><<<dim3(64, 16), 256, 0, stream>>>(
      xb, Wq_t, qf, 8192, 512, nullptr, scal + 0, scal + 0);
  k_gemm_bs<768, false, true><<<dim3(16, 32), 256, 0, stream>>>(
      cb, Wk_t, kvf, 2048, 1024, nullptr, scal + 1, scal + 2);
  k_quant_kv<<<1280, 256, 0, stream>>>(kvf, k8, v8t, scal);
  k_pass1<<<dim3(64, 16), 256, 0, stream>>>(qf, q8, k8, invz, scal);
  k_pass2<<<dim3(64, 16), 256, 0, stream>>>(q8, k8, v8t, invz, scal, o);
  k_gemm_bs<512, true, false><<<dim3(64, 16), 256, 0, stream>>>(
      o, Wo_t, out, 8192, 512, bo, nullptr, nullptr);
}

// Round 8
// 201.795 us; speedup vs baseline: 1.0896x; 1.0126x over previous
//
#include <hip/hip_runtime.h>
#include <stdint.h>

typedef float  v4f  __attribute__((ext_vector_type(4)));
typedef int    v4i  __attribute__((ext_vector_type(4)));
typedef __bf16 v8bf __attribute__((ext_vector_type(8)));
typedef __bf16 v4bf __attribute__((ext_vector_type(4)));

#define BATCH  2
#define NQ     4096
#define MK     1024
#define DMODEL 512
#define DCTX   768
#define NH     8
#define DH     64

// W[K][512] fp32 -> Wt[512][K] bf16; block (0,0,0) also zero-inits scal[0..3]
__global__ __launch_bounds__(256) void k_wtrans(
    const float* __restrict__ Wq, const float* __restrict__ Wk,
    const float* __restrict__ Wv, const float* __restrict__ Wo,
    __bf16* __restrict__ Wq_t, __bf16* __restrict__ Wk_t,
    __bf16* __restrict__ Wv_t, __bf16* __restrict__ Wo_t,
    unsigned* __restrict__ scal) {
  if (blockIdx.x == 0 && blockIdx.y == 0 && blockIdx.z == 0 && threadIdx.x < 4)
    scal[threadIdx.x] = 0u;
  const float* src; __bf16* dst; int K;
  switch (blockIdx.z) {
    case 0:  src = Wq; dst = Wq_t; K = DMODEL; break;
    case 1:  src = Wk; dst = Wk_t; K = DCTX;   break;
    case 2:  src = Wv; dst = Wv_t; K = DCTX;   break;
    default: src = Wo; dst = Wo_t; K = DMODEL; break;
  }
  int k0 = blockIdx.y * 32;
  if (k0 >= K) return;
  int n0 = blockIdx.x * 32;
  __shared__ __bf16 tile[32][33];
  int c = threadIdx.x & 31, r0 = threadIdx.x >> 5;
  for (int i = 0; i < 4; ++i) {
    int r = r0 + i * 8;
    tile[c][r] = (__bf16)src[(size_t)(k0 + r) * DMODEL + n0 + c];
  }
  __syncthreads();
  for (int i = 0; i < 4; ++i) {
    int r = r0 + i * 8;
    dst[(size_t)(n0 + r) * K + k0 + c] = tile[r][c];
  }
}

// x and ctx fp32 -> bf16 (same RNE cvt the GEMM staging applied -> bits identical).
__global__ __launch_bounds__(256) void k_cvt(
    const float* __restrict__ x, const float* __restrict__ ctx,
    __bf16* __restrict__ xb, __bf16* __restrict__ cb) {
  const int XC = BATCH * NQ * DMODEL / 8;
  const int CC = BATCH * MK * DCTX / 8;
  int idx = blockIdx.x * 256 + threadIdx.x;
  const float* src; __bf16* dst;
  if (idx < XC) { src = x + (size_t)idx * 8; dst = xb + (size_t)idx * 8; }
  else {
    int j = idx - XC;
    if (j >= CC) return;
    src = ctx + (size_t)j * 8; dst = cb + (size_t)j * 8;
  }
  float4 a = *(const float4*)src, b = *(const float4*)(src + 4);
  v8bf o = { (__bf16)a.x, (__bf16)a.y, (__bf16)a.z, (__bf16)a.w,
             (__bf16)b.x, (__bf16)b.y, (__bf16)b.z, (__bf16)b.w };
  *(v8bf*)dst = o;
}

// B-stationary GEMM: C[M][N] = A[M][K](bf16) @ Bt[N][K](bf16)^T.
// 128x32 block; 32-col B panel for ALL K in LDS (one barrier); K-loop barrier-free.
template<int K_, bool BIAS, bool AMAX>
__global__ __launch_bounds__(256, 3) void k_gemm_bs(
    const __bf16* __restrict__ A, const __bf16* __restrict__ Bt,
    float* __restrict__ C, int M, int N,
    const float* __restrict__ bias,
    unsigned* __restrict__ amaxLo, unsigned* __restrict__ amaxHi) {
  constexpr int CS = K_ + 8;
  constexpr int GPC = K_ / 8;
  __shared__ __bf16 Bs[32 * CS];
  __shared__ float redmax[4];
  const int tid = threadIdx.x;
  const int lane = tid & 63, wave = tid >> 6;
  const int l15 = lane & 15, g = lane >> 4;
  const int col0 = blockIdx.y * 32;
  const int row0w = blockIdx.x * 128 + wave * 32;

#pragma unroll
  for (int i = 0; i < GPC * 32 / 256; ++i) {
    int f = i * 256 + tid;
    int c = f / GPC, w = f - c * GPC;
    *(v8bf*)(&Bs[c * CS + w * 8]) =
        *(const v8bf*)(Bt + (size_t)(col0 + c) * K_ + w * 8);
  }
  __syncthreads();

  v4f acc[2][2] = {};
  const __bf16* a0 = A + (size_t)(row0w + l15) * K_ + g * 8;
  const __bf16* a1 = A + (size_t)(row0w + 16 + l15) * K_ + g * 8;
#pragma unroll
  for (int k0 = 0; k0 < K_; k0 += 32) {
    v8bf af0 = *(const v8bf*)(a0 + k0);
    v8bf af1 = *(const v8bf*)(a1 + k0);
    v8bf bf0 = *(const v8bf*)(&Bs[l15 * CS + k0 + g * 8]);
    v8bf bf1 = *(const v8bf*)(&Bs[(16 + l15) * CS + k0 + g * 8]);
    acc[0][0] = __builtin_amdgcn_mfma_f32_16x16x32_bf16(af0, bf0, acc[0][0], 0, 0, 0);
    acc[0][1] = __builtin_amdgcn_mfma_f32_16x16x32_bf16(af0, bf1, acc[0][1], 0, 0, 0);
    acc[1][0] = __builtin_amdgcn_mfma_f32_16x16x32_bf16(af1, bf0, acc[1][0], 0, 0, 0);
    acc[1][1] = __builtin_amdgcn_mfma_f32_16x16x32_bf16(af1, bf1, acc[1][1], 0, 0, 0);
  }

  float lmax = 0.0f;
#pragma unroll
  for (int j = 0; j < 2; ++j) {
    int col = col0 + j * 16 + l15;
    float bv = BIAS ? bias[col] : 0.0f;
#pragma unroll
    for (int i = 0; i < 2; ++i) {
#pragma unroll
      for (int r = 0; r < 4; ++r) {
        int row = row0w + i * 16 + g * 4 + r;
        float cv = acc[i][j][r] + bv;
        C[(size_t)row * N + col] = cv;
        if (AMAX) lmax = fmaxf(lmax, fabsf(cv));
      }
    }
  }
  if (AMAX) {
    for (int off = 32; off > 0; off >>= 1)
      lmax = fmaxf(lmax, __shfl_xor(lmax, off, 64));
    if (lane == 0) redmax[wave] = lmax;
    __syncthreads();
    if (tid == 0) {
      float bm = fmaxf(fmaxf(redmax[0], redmax[1]), fmaxf(redmax[2], redmax[3]));
      atomicMax(col0 < 512 ? amaxLo : amaxHi, __float_as_uint(bm));
    }
  }
}

// k/v quantization: blocks [0,1024) quantize k; [1024,1280) transpose-quantize v.
__global__ __launch_bounds__(256) void k_quant_kv(
    const float* __restrict__ kvf,
    int8_t* __restrict__ k8, int8_t* __restrict__ v8t,
    const unsigned* __restrict__ scal) {
  __shared__ int8_t tile[64][80];
  int bx = blockIdx.x;
  if (bx < 1024) {
    int j = bx * 256 + threadIdx.x;
    int r = j >> 7;
    int c4 = (j & 127) << 2;
    float4 v = *(const float4*)(kvf + (size_t)r * 1024 + c4);
    float s = 127.0f / __uint_as_float(scal[1]);
    int a0 = __float2int_rn(v.x * s), a1 = __float2int_rn(v.y * s);
    int a2 = __float2int_rn(v.z * s), a3 = __float2int_rn(v.w * s);
    a0 = max(-128, min(127, a0)); a1 = max(-128, min(127, a1));
    a2 = max(-128, min(127, a2)); a3 = max(-128, min(127, a3));
    unsigned p = (unsigned)(a0 & 255) | ((unsigned)(a1 & 255) << 8) |
                 ((unsigned)(a2 & 255) << 16) | ((unsigned)(a3 & 255) << 24);
    *(unsigned*)(k8 + (size_t)j * 4) = p;
    return;
  }
  int id = bx - 1024;
  int bh = id >> 4, b = bh >> 3, h = bh & 7;
  int j0 = (id & 15) * 64;
  const float s = 127.0f / __uint_as_float(scal[2]);
  int t = threadIdx.x;
  int j = t >> 2, dh0 = (t & 3) << 4;
  const float* src = kvf + (size_t)(b * MK + j0 + j) * 1024 + 512 + h * DH + dh0;
#pragma unroll
  for (int i = 0; i < 16; i += 4) {
    float4 v = *(const float4*)(src + i);
    int a0 = __float2int_rn(v.x * s), a1 = __float2int_rn(v.y * s);
    int a2 = __float2int_rn(v.z * s), a3 = __float2int_rn(v.w * s);
    tile[dh0 + i + 0][j] = (int8_t)max(-128, min(127, a0));
    tile[dh0 + i + 1][j] = (int8_t)max(-128, min(127, a1));
    tile[dh0 + i + 2][j] = (int8_t)max(-128, min(127, a2));
    tile[dh0 + i + 3][j] = (int8_t)max(-128, min(127, a3));
  }
  __syncthreads();
  int dh = t >> 2, jb = (t & 3) << 4;
  v4i val = *(const v4i*)(&tile[dh][jb]);
  *(v4i*)(v8t + (size_t)(bh * DH + dh) * MK + j0 + jb) = val;
}

__device__ __forceinline__ v4i quant_pack16(const float* p, float s) {
  v4i out;
#pragma unroll
  for (int q = 0; q < 4; ++q) {
    float4 v = *(const float4*)(p + q * 4);
    int a0 = __float2int_rn(v.x * s), a1 = __float2int_rn(v.y * s);
    int a2 = __float2int_rn(v.z * s), a3 = __float2int_rn(v.w * s);
    a0 = max(-128, min(127, a0)); a1 = max(-128, min(127, a1));
    a2 = max(-128, min(127, a2)); a3 = max(-128, min(127, a3));
    out[q] = (int)((unsigned)(a0 & 255) | ((unsigned)(a1 & 255) << 8) |
                   ((unsigned)(a2 & 255) << 16) | ((unsigned)(a3 & 255) << 24));
  }
  return out;
}

// pass 1 v4: waves split q-rows (16 each); block loops 8 tiles of 128 keys with
// k staged in block-shared LDS (no big register arrays -> no compiler reloads).
// z kept as 4 per-quarter accumulators; per-lane partial -> xor16/32 g-tree ->
// (q0+q1)+(q2+q3): bit-identical summation tree to v3.
__global__ __launch_bounds__(256, 4) void k_pass1(
    const float* __restrict__ qf, int8_t* __restrict__ q8,
    const int8_t* __restrict__ k8,
    float* __restrict__ invz, unsigned* __restrict__ scal) {
  __shared__ __align__(16) int8_t kbuf[128 * 72];   // 9 KB, stride 72 ~2-way banks
  __shared__ float mared[4];
  int bh = blockIdx.y, b = bh >> 3, h = bh & 7;
  int wave = threadIdx.x >> 6, lane = threadIdx.x & 63;
  int l15 = lane & 15, g = lane >> 4;
  int row0 = blockIdx.x * 64;
  int myrow = row0 + wave * 16 + l15;
  const float aq = __uint_as_float(scal[0]), ak = __uint_as_float(scal[1]);
  const float alpha2 = (aq * ak) * (0.125f / (127.0f * 127.0f)) * 1.44269504f;
  const float sq = 127.0f / aq;
  const v4i z4 = {0, 0, 0, 0};
  size_t qoff = (size_t)(b * NQ + myrow) * DMODEL + h * DH + g * 16;
  v4i qfrag = quant_pack16(qf + qoff, sq);
  *(v4i*)(q8 + qoff) = qfrag;
  const int8_t* kbase = k8 + (size_t)b * MK * DMODEL + h * DH;
  const int rs = threadIdx.x >> 2, qs = (threadIdx.x & 3) * 16;

  float z[4] = {0.f, 0.f, 0.f, 0.f};
  int mi = -(1 << 30);
  for (int tile = 0; tile < 8; ++tile) {
    __syncthreads();
    *(v4i*)(&kbuf[rs * 72 + qs]) =
        *(const v4i*)(kbase + (size_t)(tile * 128 + rs) * DMODEL + qs);
    *(v4i*)(&kbuf[(rs + 64) * 72 + qs]) =
        *(const v4i*)(kbase + (size_t)(tile * 128 + rs + 64) * DMODEL + qs);
    __syncthreads();
    float zt = z[tile >> 1];
#pragma unroll
    for (int t = 0; t < 8; ++t) {
      v4i kfrag = *(const v4i*)(&kbuf[(t * 16 + l15) * 72 + g * 16]);
      v4i sa = __builtin_amdgcn_mfma_i32_16x16x64_i8(kfrag, qfrag, z4, 0, 0, 0);
      mi = max(mi, max(max(sa[0], sa[1]), max(sa[2], sa[3])));
      float e0 = __builtin_amdgcn_exp2f((float)sa[0] * alpha2);
      float e1 = __builtin_amdgcn_exp2f((float)sa[1] * alpha2);
      float e2 = __builtin_amdgcn_exp2f((float)sa[2] * alpha2);
      float e3 = __builtin_amdgcn_exp2f((float)sa[3] * alpha2);
      zt += (e0 + e1) + (e2 + e3);
    }
    z[tile >> 1] = zt;
  }
#pragma unroll
  for (int i = 0; i < 4; ++i) {
    z[i] += __shfl_xor(z[i], 16, 64);
    z[i] += __shfl_xor(z[i], 32, 64);
  }
  mi = max(mi, __shfl_xor(mi, 16, 64));
  mi = max(mi, __shfl_xor(mi, 32, 64));
  float zt = (z[0] + z[1]) + (z[2] + z[3]);
  float iz = 1.0f / zt;
  if (g == 0) invz[(size_t)bh * NQ + myrow] = iz;
  float ma = __builtin_amdgcn_exp2f((float)mi * alpha2) * iz;  // row softmax max
#pragma unroll
  for (int off = 1; off < 16; off <<= 1)
    ma = fmaxf(ma, __shfl_xor(ma, off, 64));
  if (lane == 0) mared[wave] = ma;
  __syncthreads();
  if (threadIdx.x == 0)
    atomicMax(scal + 3,
              __float_as_uint(fmaxf(fmaxf(mared[0], mared[1]),
                                    fmaxf(mared[2], mared[3]))));
}

// pass 2 v6: waves split q-rows (16 each); 8 tiles of 128 keys with k (9 KB) and
// v (9.5 KB) in block-shared LDS; attn round-trip per wave in LDS (9.5 KB).
// pacc accumulates the exact int32 sum over all keys -> bit-identical output.
__global__ __launch_bounds__(256, 4) void k_pass2(
    const int8_t* __restrict__ q8, const int8_t* __restrict__ k8,
    const int8_t* __restrict__ v8t, const float* __restrict__ invz,
    const unsigned* __restrict__ scal, __bf16* __restrict__ o) {
  __shared__ __align__(16) int8_t kbuf[128 * 72];       // stride 72: ~2-way banks
  __shared__ __align__(16) int8_t vbuf[64 * 152];       // stride 152: ~2-way
  __shared__ __align__(16) int8_t albuf[4][16 * 152];   // wave-private attn tile
  int bh = blockIdx.y, b = bh >> 3, h = bh & 7;
  int wave = threadIdx.x >> 6, lane = threadIdx.x & 63;
  int l15 = lane & 15, g = lane >> 4;
  int row0 = blockIdx.x * 64;
  int myrow = row0 + wave * 16 + l15;
  const float aq = __uint_as_float(scal[0]), ak = __uint_as_float(scal[1]);
  const float avv = __uint_as_float(scal[2]), izm = __uint_as_float(scal[3]);
  const float alpha2 = (aq * ak) * (0.125f / (127.0f * 127.0f)) * 1.44269504f;
  const float oscale = (izm / 127.0f) * (avv / 127.0f);
  const float MAGIC = 12582912.0f;  // 1.5 * 2^23
  const v4i z4 = {0, 0, 0, 0};

  v4i qfrag = *(const v4i*)(q8 + (size_t)(b * NQ + myrow) * DMODEL + h * DH + g * 16);
  const float lcr = __builtin_amdgcn_logf(invz[(size_t)bh * NQ + myrow] * (127.0f / izm));
  const int8_t* kbase = k8 + (size_t)b * MK * DMODEL + h * DH;
  const int8_t* vbase = v8t + (size_t)bh * DH * MK;
  int8_t* alds = albuf[wave];
  const int rs = threadIdx.x >> 2, qs = (threadIdx.x & 3) * 16;   // k staging
  const int vr = threadIdx.x >> 3, vq = (threadIdx.x & 7) * 16;   // v staging

  v4i pacc[4] = {};
  for (int tile = 0; tile < 8; ++tile) {
    __syncthreads();
    *(v4i*)(&kbuf[rs * 72 + qs]) =
        *(const v4i*)(kbase + (size_t)(tile * 128 + rs) * DMODEL + qs);
    *(v4i*)(&kbuf[(rs + 64) * 72 + qs]) =
        *(const v4i*)(kbase + (size_t)(tile * 128 + rs + 64) * DMODEL + qs);
    *(v4i*)(&vbuf[vr * 152 + vq]) =
        *(const v4i*)(vbase + (size_t)vr * MK + tile * 128 + vq);
    *(v4i*)(&vbuf[(vr + 32) * 152 + vq]) =
        *(const v4i*)(vbase + (size_t)(vr + 32) * MK + tile * 128 + vq);
    __syncthreads();
    // QK + quantize -> albuf (wave-private; DS in-order per wave -> no barrier)
#pragma unroll
    for (int t = 0; t < 8; ++t) {
      v4i kfrag = *(const v4i*)(&kbuf[(t * 16 + l15) * 72 + g * 16]);
      v4i sa = __builtin_amdgcn_mfma_i32_16x16x64_i8(kfrag, qfrag, z4, 0, 0, 0);
      float f0 = __builtin_amdgcn_exp2f(fmaf((float)sa[0], alpha2, lcr)) + MAGIC;
      float f1 = __builtin_amdgcn_exp2f(fmaf((float)sa[1], alpha2, lcr)) + MAGIC;
      float f2 = __builtin_amdgcn_exp2f(fmaf((float)sa[2], alpha2, lcr)) + MAGIC;
      float f3 = __builtin_amdgcn_exp2f(fmaf((float)sa[3], alpha2, lcr)) + MAGIC;
      unsigned packed = (__float_as_uint(f0) & 255u) |
                        ((__float_as_uint(f1) & 255u) << 8) |
                        ((__float_as_uint(f2) & 255u) << 16) |
                        (__float_as_uint(f3) << 24);
      // C-layout: col(l15)=q-row, row(g*4+r)=key -> [qrow][key_local]
      *(unsigned*)(alds + l15 * 152 + t * 16 + g * 4) = packed;
    }
    // PV
#pragma unroll
    for (int c = 0; c < 2; ++c) {
      v4i afrag = *(const v4i*)(alds + l15 * 152 + c * 64 + g * 16);
#pragma unroll
      for (int d = 0; d < 4; ++d) {
        v4i bfrag = *(const v4i*)(&vbuf[(d * 16 + l15) * 152 + c * 64 + g * 16]);
        pacc[d] = __builtin_amdgcn_mfma_i32_16x16x64_i8(afrag, bfrag, pacc[d], 0, 0, 0);
      }
    }
  }
  // epilogue: C[m=qrow g*4+r][n=dh d*16+l15]
  __bf16* obase = o + (size_t)(b * NQ + row0 + wave * 16) * DMODEL + h * DH;
#pragma unroll
  for (int d = 0; d < 4; ++d)
#pragma unroll
    for (int r = 0; r < 4; ++r)
      obase[(size_t)(g * 4 + r) * DMODEL + d * 16 + l15] =
          (__bf16)((float)pacc[d][r] * oscale);
}

extern "C" void kernel_launch(void* const* d_in, const int* in_sizes, int n_in,
                              void* d_out, int out_size, void* d_ws, size_t ws_size,
                              hipStream_t stream) {
  (void)in_sizes; (void)n_in; (void)out_size; (void)ws_size;
  const float* x   = (const float*)d_in[0];
  const float* ctx = (const float*)d_in[1];
  const float* Wq  = (const float*)d_in[2];
  const float* Wk  = (const float*)d_in[3];
  const float* Wv  = (const float*)d_in[4];
  const float* Wo  = (const float*)d_in[5];
  const float* bo  = (const float*)d_in[6];
  float* out = (float*)d_out;

  char* ws = (char*)d_ws;
  size_t off = 0;
  auto alloc = [&](size_t bytes) {
    char* p = ws + off;
    off += (bytes + 255) & ~(size_t)255;
    return p;
  };
  unsigned* scal = (unsigned*)alloc(16);
  __bf16* Wq_t = (__bf16*)alloc((size_t)512 * 512 * 2);
  __bf16* Wk_t = (__bf16*)alloc((size_t)512 * 768 * 2);  // contiguous with Wv_t
  __bf16* Wv_t = (__bf16*)alloc((size_t)512 * 768 * 2);
  __bf16* Wo_t = (__bf16*)alloc((size_t)512 * 512 * 2);
  __bf16* xb   = (__bf16*)alloc((size_t)BATCH * NQ * DMODEL * 2);
  __bf16* cb   = (__bf16*)alloc((size_t)BATCH * MK * DCTX * 2);
  float* qf  = (float*)alloc((size_t)BATCH * NQ * DMODEL * 4);   // later reused as o
  float* kvf = (float*)alloc((size_t)BATCH * MK * 1024 * 4);     // [2048][1024]: k | v
  int8_t* q8 = (int8_t*)alloc((size_t)BATCH * NQ * DMODEL);
  int8_t* k8 = (int8_t*)alloc((size_t)BATCH * MK * DMODEL);
  int8_t* v8t = (int8_t*)alloc((size_t)BATCH * NH * DH * MK);
  float* invz = (float*)alloc((size_t)BATCH * NH * NQ * 4);
  __bf16* o = (__bf16*)qf;  // q_f32 dead after pass1 quantizes it

  k_wtrans<<<dim3(16, 24, 4), 256, 0, stream>>>(Wq, Wk, Wv, Wo, Wq_t, Wk_t, Wv_t, Wo_t, scal);
  k_cvt<<<2816, 256, 0, stream>>>(x, ctx, xb, cb);
  k_gemm_bs<512, false, true><<<dim3(64, 16), 256, 0, stream>>>(
      xb, Wq_t, qf, 8192, 512, nullptr, scal + 0, scal + 0);
  k_gemm_bs<768, false, true><<<dim3(16, 32), 256, 0, stream>>>(
      cb, Wk_t, kvf, 2048, 1024, nullptr, scal + 1, scal + 2);
  k_quant_kv<<<1280, 256, 0, stream>>>(kvf, k8, v8t, scal);
  k_pass1<<<dim3(64, 16), 256, 0, stream>>>(qf, q8, k8, invz, scal);
  k_pass2<<<dim3(64, 16), 256, 0, stream>>>(q8, k8, v8t, invz, scal, o);
  k_gemm_bs<512, true, false><<<dim3(64, 16), 256, 0, stream>>>(
      o, Wo_t, out, 8192, 512, bo, nullptr, nullptr);
}

// Round 9
// 186.962 us; speedup vs baseline: 1.1760x; 1.0793x over previous
//
#include <hip/hip_runtime.h>
#include <stdint.h>

typedef float  v4f  __attribute__((ext_vector_type(4)));
typedef int    v4i  __attribute__((ext_vector_type(4)));
typedef __bf16 v8bf __attribute__((ext_vector_type(8)));
typedef __bf16 v4bf __attribute__((ext_vector_type(4)));

#define BATCH  2
#define NQ     4096
#define MK     1024
#define DMODEL 512
#define DCTX   768
#define NH     8
#define DH     64

// Merged prep: blocks [0,2816) convert x/ctx fp32->bf16 (RNE, same as GEMM
// staging did -> bits identical); blocks [2816,4352) transpose weights to
// Wt[512][K] bf16. Block 2816 zero-inits scal (kernel boundary orders it
// before the GEMM-epilogue atomics).
__global__ __launch_bounds__(256) void k_prep(
    const float* __restrict__ x, const float* __restrict__ ctx,
    __bf16* __restrict__ xb, __bf16* __restrict__ cb,
    const float* __restrict__ Wq, const float* __restrict__ Wk,
    const float* __restrict__ Wv, const float* __restrict__ Wo,
    __bf16* __restrict__ Wq_t, __bf16* __restrict__ Wk_t,
    __bf16* __restrict__ Wv_t, __bf16* __restrict__ Wo_t,
    unsigned* __restrict__ scal) {
  int bx = blockIdx.x;
  if (bx < 2816) {
    const int XC = BATCH * NQ * DMODEL / 8;
    const int CC = BATCH * MK * DCTX / 8;
    int idx = bx * 256 + threadIdx.x;
    const float* src; __bf16* dst;
    if (idx < XC) { src = x + (size_t)idx * 8; dst = xb + (size_t)idx * 8; }
    else {
      int j = idx - XC;
      if (j >= CC) return;
      src = ctx + (size_t)j * 8; dst = cb + (size_t)j * 8;
    }
    float4 a = *(const float4*)src, b = *(const float4*)(src + 4);
    v8bf o = { (__bf16)a.x, (__bf16)a.y, (__bf16)a.z, (__bf16)a.w,
               (__bf16)b.x, (__bf16)b.y, (__bf16)b.z, (__bf16)b.w };
    *(v8bf*)dst = o;
    return;
  }
  int id = bx - 2816;
  if (id == 0 && threadIdx.x < 4) scal[threadIdx.x] = 0u;
  int tx = id & 15, rem = id >> 4;
  int ty = rem % 24, tz = rem / 24;
  const float* src; __bf16* dst; int K;
  switch (tz) {
    case 0:  src = Wq; dst = Wq_t; K = DMODEL; break;
    case 1:  src = Wk; dst = Wk_t; K = DCTX;   break;
    case 2:  src = Wv; dst = Wv_t; K = DCTX;   break;
    default: src = Wo; dst = Wo_t; K = DMODEL; break;
  }
  int k0 = ty * 32;
  if (k0 >= K) return;
  int n0 = tx * 32;
  __shared__ __bf16 tile[32][33];
  int c = threadIdx.x & 31, r0 = threadIdx.x >> 5;
  for (int i = 0; i < 4; ++i) {
    int r = r0 + i * 8;
    tile[c][r] = (__bf16)src[(size_t)(k0 + r) * DMODEL + n0 + c];
  }
  __syncthreads();
  for (int i = 0; i < 4; ++i) {
    int r = r0 + i * 8;
    dst[(size_t)(n0 + r) * K + k0 + c] = tile[r][c];
  }
}

// B-stationary GEMM: C[M][N] = A[M][K](bf16) @ Bt[N][K](bf16)^T.
// 128-row x NC-col block; NC-col B panel for ALL K in LDS (one barrier);
// K-loop barrier-free. Per-element k-ascending MFMA chain identical for any
// NC -> bit-identical C.
template<int K_, int NC, bool BIAS, bool AMAX, int OCC>
__global__ __launch_bounds__(256, OCC) void k_gemm_bs(
    const __bf16* __restrict__ A, const __bf16* __restrict__ Bt,
    float* __restrict__ C, int M, int N,
    const float* __restrict__ bias,
    unsigned* __restrict__ amaxLo, unsigned* __restrict__ amaxHi) {
  constexpr int CS = K_ + 8;
  constexpr int GPC = K_ / 8;
  constexpr int JT = NC / 16;
  __shared__ __bf16 Bs[NC * CS];
  __shared__ float redmax[4];
  const int tid = threadIdx.x;
  const int lane = tid & 63, wave = tid >> 6;
  const int l15 = lane & 15, g = lane >> 4;
  const int col0 = blockIdx.y * NC;
  const int row0w = blockIdx.x * 128 + wave * 32;

#pragma unroll
  for (int i = 0; i < NC * GPC / 256; ++i) {
    int f = i * 256 + tid;
    int c = f / GPC, w = f - c * GPC;
    *(v8bf*)(&Bs[c * CS + w * 8]) =
        *(const v8bf*)(Bt + (size_t)(col0 + c) * K_ + w * 8);
  }
  __syncthreads();

  v4f acc[2][JT] = {};
  const __bf16* a0 = A + (size_t)(row0w + l15) * K_ + g * 8;
  const __bf16* a1 = A + (size_t)(row0w + 16 + l15) * K_ + g * 8;
#pragma unroll
  for (int k0 = 0; k0 < K_; k0 += 32) {
    v8bf af0 = *(const v8bf*)(a0 + k0);
    v8bf af1 = *(const v8bf*)(a1 + k0);
#pragma unroll
    for (int j = 0; j < JT; ++j) {
      v8bf bfj = *(const v8bf*)(&Bs[(j * 16 + l15) * CS + k0 + g * 8]);
      acc[0][j] = __builtin_amdgcn_mfma_f32_16x16x32_bf16(af0, bfj, acc[0][j], 0, 0, 0);
      acc[1][j] = __builtin_amdgcn_mfma_f32_16x16x32_bf16(af1, bfj, acc[1][j], 0, 0, 0);
    }
  }

  float lmax = 0.0f;
#pragma unroll
  for (int j = 0; j < JT; ++j) {
    int col = col0 + j * 16 + l15;
    float bv = BIAS ? bias[col] : 0.0f;
#pragma unroll
    for (int i = 0; i < 2; ++i) {
#pragma unroll
      for (int r = 0; r < 4; ++r) {
        int row = row0w + i * 16 + g * 4 + r;  // C/D: col=lane&15, row=quad*4+reg
        float cv = acc[i][j][r] + bv;
        C[(size_t)row * N + col] = cv;
        if (AMAX) lmax = fmaxf(lmax, fabsf(cv));
      }
    }
  }
  if (AMAX) {
    for (int off = 32; off > 0; off >>= 1)
      lmax = fmaxf(lmax, __shfl_xor(lmax, off, 64));
    if (lane == 0) redmax[wave] = lmax;
    __syncthreads();
    if (tid == 0) {
      float bm = fmaxf(fmaxf(redmax[0], redmax[1]), fmaxf(redmax[2], redmax[3]));
      atomicMax(col0 < 512 ? amaxLo : amaxHi, __float_as_uint(bm));
    }
  }
}

// k/v quantization: blocks [0,1024) quantize k; [1024,1280) transpose-quantize v.
__global__ __launch_bounds__(256) void k_quant_kv(
    const float* __restrict__ kvf,
    int8_t* __restrict__ k8, int8_t* __restrict__ v8t,
    const unsigned* __restrict__ scal) {
  __shared__ int8_t tile[64][80];
  int bx = blockIdx.x;
  if (bx < 1024) {
    int j = bx * 256 + threadIdx.x;
    int r = j >> 7;
    int c4 = (j & 127) << 2;
    float4 v = *(const float4*)(kvf + (size_t)r * 1024 + c4);
    float s = 127.0f / __uint_as_float(scal[1]);
    int a0 = __float2int_rn(v.x * s), a1 = __float2int_rn(v.y * s);
    int a2 = __float2int_rn(v.z * s), a3 = __float2int_rn(v.w * s);
    a0 = max(-128, min(127, a0)); a1 = max(-128, min(127, a1));
    a2 = max(-128, min(127, a2)); a3 = max(-128, min(127, a3));
    unsigned p = (unsigned)(a0 & 255) | ((unsigned)(a1 & 255) << 8) |
                 ((unsigned)(a2 & 255) << 16) | ((unsigned)(a3 & 255) << 24);
    *(unsigned*)(k8 + (size_t)j * 4) = p;
    return;
  }
  int id = bx - 1024;
  int bh = id >> 4, b = bh >> 3, h = bh & 7;
  int j0 = (id & 15) * 64;
  const float s = 127.0f / __uint_as_float(scal[2]);
  int t = threadIdx.x;
  int j = t >> 2, dh0 = (t & 3) << 4;
  const float* src = kvf + (size_t)(b * MK + j0 + j) * 1024 + 512 + h * DH + dh0;
#pragma unroll
  for (int i = 0; i < 16; i += 4) {
    float4 v = *(const float4*)(src + i);
    int a0 = __float2int_rn(v.x * s), a1 = __float2int_rn(v.y * s);
    int a2 = __float2int_rn(v.z * s), a3 = __float2int_rn(v.w * s);
    tile[dh0 + i + 0][j] = (int8_t)max(-128, min(127, a0));
    tile[dh0 + i + 1][j] = (int8_t)max(-128, min(127, a1));
    tile[dh0 + i + 2][j] = (int8_t)max(-128, min(127, a2));
    tile[dh0 + i + 3][j] = (int8_t)max(-128, min(127, a3));
  }
  __syncthreads();
  int dh = t >> 2, jb = (t & 3) << 4;
  v4i val = *(const v4i*)(&tile[dh][jb]);
  *(v4i*)(v8t + (size_t)(bh * DH + dh) * MK + j0 + jb) = val;
}

__device__ __forceinline__ v4i quant_pack16(const float* p, float s) {
  v4i out;
#pragma unroll
  for (int q = 0; q < 4; ++q) {
    float4 v = *(const float4*)(p + q * 4);
    int a0 = __float2int_rn(v.x * s), a1 = __float2int_rn(v.y * s);
    int a2 = __float2int_rn(v.z * s), a3 = __float2int_rn(v.w * s);
    a0 = max(-128, min(127, a0)); a1 = max(-128, min(127, a1));
    a2 = max(-128, min(127, a2)); a3 = max(-128, min(127, a3));
    out[q] = (int)((unsigned)(a0 & 255) | ((unsigned)(a1 & 255) << 8) |
                   ((unsigned)(a2 & 255) << 16) | ((unsigned)(a3 & 255) << 24));
  }
  return out;
}

// pass 1: waves split q-rows (16 each); 8 tiles of 128 keys staged in LDS.
// z summation tree identical to prior rounds -> bit-identical invz.
__global__ __launch_bounds__(256, 4) void k_pass1(
    const float* __restrict__ qf, int8_t* __restrict__ q8,
    const int8_t* __restrict__ k8,
    float* __restrict__ invz, unsigned* __restrict__ scal) {
  __shared__ __align__(16) int8_t kbuf[128 * 72];
  __shared__ float mared[4];
  int bh = blockIdx.y, b = bh >> 3, h = bh & 7;
  int wave = threadIdx.x >> 6, lane = threadIdx.x & 63;
  int l15 = lane & 15, g = lane >> 4;
  int row0 = blockIdx.x * 64;
  int myrow = row0 + wave * 16 + l15;
  const float aq = __uint_as_float(scal[0]), ak = __uint_as_float(scal[1]);
  const float alpha2 = (aq * ak) * (0.125f / (127.0f * 127.0f)) * 1.44269504f;
  const float sq = 127.0f / aq;
  const v4i z4 = {0, 0, 0, 0};
  size_t qoff = (size_t)(b * NQ + myrow) * DMODEL + h * DH + g * 16;
  v4i qfrag = quant_pack16(qf + qoff, sq);
  *(v4i*)(q8 + qoff) = qfrag;
  const int8_t* kbase = k8 + (size_t)b * MK * DMODEL + h * DH;
  const int rs = threadIdx.x >> 2, qs = (threadIdx.x & 3) * 16;

  float z[4] = {0.f, 0.f, 0.f, 0.f};
  int mi = -(1 << 30);
  for (int tile = 0; tile < 8; ++tile) {
    __syncthreads();
    *(v4i*)(&kbuf[rs * 72 + qs]) =
        *(const v4i*)(kbase + (size_t)(tile * 128 + rs) * DMODEL + qs);
    *(v4i*)(&kbuf[(rs + 64) * 72 + qs]) =
        *(const v4i*)(kbase + (size_t)(tile * 128 + rs + 64) * DMODEL + qs);
    __syncthreads();
    float zt = z[tile >> 1];
#pragma unroll
    for (int t = 0; t < 8; ++t) {
      v4i kfrag = *(const v4i*)(&kbuf[(t * 16 + l15) * 72 + g * 16]);
      v4i sa = __builtin_amdgcn_mfma_i32_16x16x64_i8(kfrag, qfrag, z4, 0, 0, 0);
      mi = max(mi, max(max(sa[0], sa[1]), max(sa[2], sa[3])));
      float e0 = __builtin_amdgcn_exp2f((float)sa[0] * alpha2);
      float e1 = __builtin_amdgcn_exp2f((float)sa[1] * alpha2);
      float e2 = __builtin_amdgcn_exp2f((float)sa[2] * alpha2);
      float e3 = __builtin_amdgcn_exp2f((float)sa[3] * alpha2);
      zt += (e0 + e1) + (e2 + e3);
    }
    z[tile >> 1] = zt;
  }
#pragma unroll
  for (int i = 0; i < 4; ++i) {
    z[i] += __shfl_xor(z[i], 16, 64);
    z[i] += __shfl_xor(z[i], 32, 64);
  }
  mi = max(mi, __shfl_xor(mi, 16, 64));
  mi = max(mi, __shfl_xor(mi, 32, 64));
  float zt = (z[0] + z[1]) + (z[2] + z[3]);
  float iz = 1.0f / zt;
  if (g == 0) invz[(size_t)bh * NQ + myrow] = iz;
  float ma = __builtin_amdgcn_exp2f((float)mi * alpha2) * iz;  // row softmax max
#pragma unroll
  for (int off = 1; off < 16; off <<= 1)
    ma = fmaxf(ma, __shfl_xor(ma, off, 64));
  if (lane == 0) mared[wave] = ma;
  __syncthreads();
  if (threadIdx.x == 0)
    atomicMax(scal + 3,
              __float_as_uint(fmaxf(fmaxf(mared[0], mared[1]),
                                    fmaxf(mared[2], mared[3]))));
}

// pass 2: waves split q-rows; k/v tiles in block LDS; wave-private attn
// round-trip; exact int32 PV accumulation -> bit-identical output.
__global__ __launch_bounds__(256, 4) void k_pass2(
    const int8_t* __restrict__ q8, const int8_t* __restrict__ k8,
    const int8_t* __restrict__ v8t, const float* __restrict__ invz,
    const unsigned* __restrict__ scal, __bf16* __restrict__ o) {
  __shared__ __align__(16) int8_t kbuf[128 * 72];
  __shared__ __align__(16) int8_t vbuf[64 * 152];
  __shared__ __align__(16) int8_t albuf[4][16 * 152];
  int bh = blockIdx.y, b = bh >> 3, h = bh & 7;
  int wave = threadIdx.x >> 6, lane = threadIdx.x & 63;
  int l15 = lane & 15, g = lane >> 4;
  int row0 = blockIdx.x * 64;
  int myrow = row0 + wave * 16 + l15;
  const float aq = __uint_as_float(scal[0]), ak = __uint_as_float(scal[1]);
  const float avv = __uint_as_float(scal[2]), izm = __uint_as_float(scal[3]);
  const float alpha2 = (aq * ak) * (0.125f / (127.0f * 127.0f)) * 1.44269504f;
  const float oscale = (izm / 127.0f) * (avv / 127.0f);
  const float MAGIC = 12582912.0f;  // 1.5 * 2^23
  const v4i z4 = {0, 0, 0, 0};

  v4i qfrag = *(const v4i*)(q8 + (size_t)(b * NQ + myrow) * DMODEL + h * DH + g * 16);
  const float lcr = __builtin_amdgcn_logf(invz[(size_t)bh * NQ + myrow] * (127.0f / izm));
  const int8_t* kbase = k8 + (size_t)b * MK * DMODEL + h * DH;
  const int8_t* vbase = v8t + (size_t)bh * DH * MK;
  int8_t* alds = albuf[wave];
  const int rs = threadIdx.x >> 2, qs = (threadIdx.x & 3) * 16;
  const int vr = threadIdx.x >> 3, vq = (threadIdx.x & 7) * 16;

  v4i pacc[4] = {};
  for (int tile = 0; tile < 8; ++tile) {
    __syncthreads();
    *(v4i*)(&kbuf[rs * 72 + qs]) =
        *(const v4i*)(kbase + (size_t)(tile * 128 + rs) * DMODEL + qs);
    *(v4i*)(&kbuf[(rs + 64) * 72 + qs]) =
        *(const v4i*)(kbase + (size_t)(tile * 128 + rs + 64) * DMODEL + qs);
    *(v4i*)(&vbuf[vr * 152 + vq]) =
        *(const v4i*)(vbase + (size_t)vr * MK + tile * 128 + vq);
    *(v4i*)(&vbuf[(vr + 32) * 152 + vq]) =
        *(const v4i*)(vbase + (size_t)(vr + 32) * MK + tile * 128 + vq);
    __syncthreads();
#pragma unroll
    for (int t = 0; t < 8; ++t) {
      v4i kfrag = *(const v4i*)(&kbuf[(t * 16 + l15) * 72 + g * 16]);
      v4i sa = __builtin_amdgcn_mfma_i32_16x16x64_i8(kfrag, qfrag, z4, 0, 0, 0);
      float f0 = __builtin_amdgcn_exp2f(fmaf((float)sa[0], alpha2, lcr)) + MAGIC;
      float f1 = __builtin_amdgcn_exp2f(fmaf((float)sa[1], alpha2, lcr)) + MAGIC;
      float f2 = __builtin_amdgcn_exp2f(fmaf((float)sa[2], alpha2, lcr)) + MAGIC;
      float f3 = __builtin_amdgcn_exp2f(fmaf((float)sa[3], alpha2, lcr)) + MAGIC;
      unsigned packed = (__float_as_uint(f0) & 255u) |
                        ((__float_as_uint(f1) & 255u) << 8) |
                        ((__float_as_uint(f2) & 255u) << 16) |
                        (__float_as_uint(f3) << 24);
      *(unsigned*)(alds + l15 * 152 + t * 16 + g * 4) = packed;
    }
#pragma unroll
    for (int c = 0; c < 2; ++c) {
      v4i afrag = *(const v4i*)(alds + l15 * 152 + c * 64 + g * 16);
#pragma unroll
      for (int d = 0; d < 4; ++d) {
        v4i bfrag = *(const v4i*)(&vbuf[(d * 16 + l15) * 152 + c * 64 + g * 16]);
        pacc[d] = __builtin_amdgcn_mfma_i32_16x16x64_i8(afrag, bfrag, pacc[d], 0, 0, 0);
      }
    }
  }
  __bf16* obase = o + (size_t)(b * NQ + row0 + wave * 16) * DMODEL + h * DH;
#pragma unroll
  for (int d = 0; d < 4; ++d)
#pragma unroll
    for (int r = 0; r < 4; ++r)
      obase[(size_t)(g * 4 + r) * DMODEL + d * 16 + l15] =
          (__bf16)((float)pacc[d][r] * oscale);
}

extern "C" void kernel_launch(void* const* d_in, const int* in_sizes, int n_in,
                              void* d_out, int out_size, void* d_ws, size_t ws_size,
                              hipStream_t stream) {
  (void)in_sizes; (void)n_in; (void)out_size; (void)ws_size;
  const float* x   = (const float*)d_in[0];
  const float* ctx = (const float*)d_in[1];
  const float* Wq  = (const float*)d_in[2];
  const float* Wk  = (const float*)d_in[3];
  const float* Wv  = (const float*)d_in[4];
  const float* Wo  = (const float*)d_in[5];
  const float* bo  = (const float*)d_in[6];
  float* out = (float*)d_out;

  char* ws = (char*)d_ws;
  size_t off = 0;
  auto alloc = [&](size_t bytes) {
    char* p = ws + off;
    off += (bytes + 255) & ~(size_t)255;
    return p;
  };
  unsigned* scal = (unsigned*)alloc(16);
  __bf16* Wq_t = (__bf16*)alloc((size_t)512 * 512 * 2);
  __bf16* Wk_t = (__bf16*)alloc((size_t)512 * 768 * 2);  // contiguous with Wv_t
  __bf16* Wv_t = (__bf16*)alloc((size_t)512 * 768 * 2);
  __bf16* Wo_t = (__bf16*)alloc((size_t)512 * 512 * 2);
  __bf16* xb   = (__bf16*)alloc((size_t)BATCH * NQ * DMODEL * 2);
  __bf16* cb   = (__bf16*)alloc((size_t)BATCH * MK * DCTX * 2);
  float* qf  = (float*)alloc((size_t)BATCH * NQ * DMODEL * 4);   // later reused as o
  float* kvf = (float*)alloc((size_t)BATCH * MK * 1024 * 4);     // [2048][1024]: k | v
  int8_t* q8 = (int8_t*)alloc((size_t)BATCH * NQ * DMODEL);
  int8_t* k8 = (int8_t*)alloc((size_t)BATCH * MK * DMODEL);
  int8_t* v8t = (int8_t*)alloc((size_t)BATCH * NH * DH * MK);
  float* invz = (float*)alloc((size_t)BATCH * NH * NQ * 4);
  __bf16* o = (__bf16*)qf;  // q_f32 dead after pass1 quantizes it

  k_prep<<<4352, 256, 0, stream>>>(x, ctx, xb, cb, Wq, Wk, Wv, Wo,
                                   Wq_t, Wk_t, Wv_t, Wo_t, scal);
  k_gemm_bs<512, 64, false, true, 2><<<dim3(64, 8), 256, 0, stream>>>(
      xb, Wq_t, qf, 8192, 512, nullptr, scal + 0, scal + 0);
  k_gemm_bs<768, 32, false, true, 3><<<dim3(16, 32), 256, 0, stream>>>(
      cb, Wk_t, kvf, 2048, 1024, nullptr, scal + 1, scal + 2);
  k_quant_kv<<<1280, 256, 0, stream>>>(kvf, k8, v8t, scal);
  k_pass1<<<dim3(64, 16), 256, 0, stream>>>(qf, q8, k8, invz, scal);
  k_pass2<<<dim3(64, 16), 256, 0, stream>>>(q8, k8, v8t, invz, scal, o);
  k_gemm_bs<512, 64, true, false, 2><<<dim3(64, 8), 256, 0, stream>>>(
      o, Wo_t, out, 8192, 512, bo, nullptr, nullptr);
}

// Round 10
// 180.704 us; speedup vs baseline: 1.2168x; 1.0346x over previous
//
#include <hip/hip_runtime.h>
#include <stdint.h>

typedef float  v4f  __attribute__((ext_vector_type(4)));
typedef int    v4i  __attribute__((ext_vector_type(4)));
typedef __bf16 v8bf __attribute__((ext_vector_type(8)));
typedef __bf16 v4bf __attribute__((ext_vector_type(4)));

#define BATCH  2
#define NQ     4096
#define MK     1024
#define DMODEL 512
#define DCTX   768
#define NH     8
#define DH     64

// Merged prep: blocks [0,2816) convert x/ctx fp32->bf16 (RNE, same as GEMM
// staging did -> bits identical); blocks [2816,4352) transpose weights to
// Wt[512][K] bf16. Block 2816 zero-inits scal.
__global__ __launch_bounds__(256) void k_prep(
    const float* __restrict__ x, const float* __restrict__ ctx,
    __bf16* __restrict__ xb, __bf16* __restrict__ cb,
    const float* __restrict__ Wq, const float* __restrict__ Wk,
    const float* __restrict__ Wv, const float* __restrict__ Wo,
    __bf16* __restrict__ Wq_t, __bf16* __restrict__ Wk_t,
    __bf16* __restrict__ Wv_t, __bf16* __restrict__ Wo_t,
    unsigned* __restrict__ scal) {
  int bx = blockIdx.x;
  if (bx < 2816) {
    const int XC = BATCH * NQ * DMODEL / 8;
    const int CC = BATCH * MK * DCTX / 8;
    int idx = bx * 256 + threadIdx.x;
    const float* src; __bf16* dst;
    if (idx < XC) { src = x + (size_t)idx * 8; dst = xb + (size_t)idx * 8; }
    else {
      int j = idx - XC;
      if (j >= CC) return;
      src = ctx + (size_t)j * 8; dst = cb + (size_t)j * 8;
    }
    float4 a = *(const float4*)src, b = *(const float4*)(src + 4);
    v8bf o = { (__bf16)a.x, (__bf16)a.y, (__bf16)a.z, (__bf16)a.w,
               (__bf16)b.x, (__bf16)b.y, (__bf16)b.z, (__bf16)b.w };
    *(v8bf*)dst = o;
    return;
  }
  int id = bx - 2816;
  if (id == 0 && threadIdx.x < 4) scal[threadIdx.x] = 0u;
  int tx = id & 15, rem = id >> 4;
  int ty = rem % 24, tz = rem / 24;
  const float* src; __bf16* dst; int K;
  switch (tz) {
    case 0:  src = Wq; dst = Wq_t; K = DMODEL; break;
    case 1:  src = Wk; dst = Wk_t; K = DCTX;   break;
    case 2:  src = Wv; dst = Wv_t; K = DCTX;   break;
    default: src = Wo; dst = Wo_t; K = DMODEL; break;
  }
  int k0 = ty * 32;
  if (k0 >= K) return;
  int n0 = tx * 32;
  __shared__ __bf16 tile[32][33];
  int c = threadIdx.x & 31, r0 = threadIdx.x >> 5;
  for (int i = 0; i < 4; ++i) {
    int r = r0 + i * 8;
    tile[c][r] = (__bf16)src[(size_t)(k0 + r) * DMODEL + n0 + c];
  }
  __syncthreads();
  for (int i = 0; i < 4; ++i) {
    int r = r0 + i * 8;
    dst[(size_t)(n0 + r) * K + k0 + c] = tile[r][c];
  }
}

// B-stationary GEMM body: C[.][N] tile = A[128 rows][K_] @ Bt[NC cols][K_]^T.
// NC-col B panel for ALL K in LDS (one barrier); K-loop barrier-free.
// Per-element k-ascending MFMA chain identical for any NC -> bit-identical C.
template<int K_, int NC, bool BIAS, bool AMAX>
__device__ __forceinline__ void gemm_body(
    char* smemraw, const __bf16* __restrict__ A, const __bf16* __restrict__ Bt,
    float* __restrict__ C, int N, int rowBlk, int colBlk,
    const float* __restrict__ bias,
    unsigned* __restrict__ amaxLo, unsigned* __restrict__ amaxHi) {
  constexpr int CS = K_ + 8;
  constexpr int GPC = K_ / 8;
  constexpr int JT = NC / 16;
  __bf16* Bs = (__bf16*)smemraw;
  float* redmax = (float*)(smemraw + (size_t)NC * CS * 2);
  const int tid = threadIdx.x;
  const int lane = tid & 63, wave = tid >> 6;
  const int l15 = lane & 15, g = lane >> 4;
  const int col0 = colBlk * NC;
  const int row0w = rowBlk * 128 + wave * 32;

#pragma unroll
  for (int i = 0; i < NC * GPC / 256; ++i) {
    int f = i * 256 + tid;
    int c = f / GPC, w = f - c * GPC;
    *(v8bf*)(&Bs[c * CS + w * 8]) =
        *(const v8bf*)(Bt + (size_t)(col0 + c) * K_ + w * 8);
  }
  __syncthreads();

  v4f acc[2][JT] = {};
  const __bf16* a0 = A + (size_t)(row0w + l15) * K_ + g * 8;
  const __bf16* a1 = A + (size_t)(row0w + 16 + l15) * K_ + g * 8;
#pragma unroll
  for (int k0 = 0; k0 < K_; k0 += 32) {
    v8bf af0 = *(const v8bf*)(a0 + k0);
    v8bf af1 = *(const v8bf*)(a1 + k0);
#pragma unroll
    for (int j = 0; j < JT; ++j) {
      v8bf bfj = *(const v8bf*)(&Bs[(j * 16 + l15) * CS + k0 + g * 8]);
      acc[0][j] = __builtin_amdgcn_mfma_f32_16x16x32_bf16(af0, bfj, acc[0][j], 0, 0, 0);
      acc[1][j] = __builtin_amdgcn_mfma_f32_16x16x32_bf16(af1, bfj, acc[1][j], 0, 0, 0);
    }
  }

  float lmax = 0.0f;
#pragma unroll
  for (int j = 0; j < JT; ++j) {
    int col = col0 + j * 16 + l15;
    float bv = BIAS ? bias[col] : 0.0f;
#pragma unroll
    for (int i = 0; i < 2; ++i) {
#pragma unroll
      for (int r = 0; r < 4; ++r) {
        int row = row0w + i * 16 + g * 4 + r;  // C/D: col=lane&15, row=quad*4+reg
        float cv = acc[i][j][r] + bv;
        C[(size_t)row * N + col] = cv;
        if (AMAX) lmax = fmaxf(lmax, fabsf(cv));
      }
    }
  }
  if (AMAX) {
    for (int off = 32; off > 0; off >>= 1)
      lmax = fmaxf(lmax, __shfl_xor(lmax, off, 64));
    if (lane == 0) redmax[wave] = lmax;
    __syncthreads();
    if (tid == 0) {
      float bm = fmaxf(fmaxf(redmax[0], redmax[1]), fmaxf(redmax[2], redmax[3]));
      atomicMax(col0 < 512 ? amaxLo : amaxHi, __float_as_uint(bm));
    }
  }
}

// Fused projections: blocks [0,512) = q GEMM (8192x512, K=512, 64-col panels);
// [512,1024) = kv GEMM (2048x1024, K=768, 32-col panels). Column panel is the
// fastest block index so consecutive blocks share the A row-panel (L2 reuse).
__global__ __launch_bounds__(256, 2) void k_gemm_qkv(
    const __bf16* __restrict__ xb, const __bf16* __restrict__ Wq_t,
    float* __restrict__ qf,
    const __bf16* __restrict__ cb, const __bf16* __restrict__ Wkv_t,
    float* __restrict__ kvf, unsigned* __restrict__ scal) {
  __shared__ __align__(16) char smem[64 * (512 + 8) * 2 + 16];
  int bid = blockIdx.x;
  if (bid < 512) {
    gemm_body<512, 64, false, true>(smem, xb, Wq_t, qf, 512,
                                    bid >> 3, bid & 7, nullptr, scal + 0, scal + 0);
  } else {
    int id = bid - 512;
    gemm_body<768, 32, false, true>(smem, cb, Wkv_t, kvf, 1024,
                                    id >> 5, id & 31, nullptr, scal + 1, scal + 2);
  }
}

__global__ __launch_bounds__(256, 2) void k_gemm_out(
    const __bf16* __restrict__ o, const __bf16* __restrict__ Wo_t,
    float* __restrict__ out, const float* __restrict__ bo) {
  __shared__ __align__(16) char smem[64 * (512 + 8) * 2 + 16];
  gemm_body<512, 64, true, false>(smem, o, Wo_t, out, 512,
                                  blockIdx.x >> 3, blockIdx.x & 7, bo,
                                  nullptr, nullptr);
}

// k/v quantization: blocks [0,1024) quantize k; [1024,1280) transpose-quantize v.
__global__ __launch_bounds__(256) void k_quant_kv(
    const float* __restrict__ kvf,
    int8_t* __restrict__ k8, int8_t* __restrict__ v8t,
    const unsigned* __restrict__ scal) {
  __shared__ int8_t tile[64][80];
  int bx = blockIdx.x;
  if (bx < 1024) {
    int j = bx * 256 + threadIdx.x;
    int r = j >> 7;
    int c4 = (j & 127) << 2;
    float4 v = *(const float4*)(kvf + (size_t)r * 1024 + c4);
    float s = 127.0f / __uint_as_float(scal[1]);
    int a0 = __float2int_rn(v.x * s), a1 = __float2int_rn(v.y * s);
    int a2 = __float2int_rn(v.z * s), a3 = __float2int_rn(v.w * s);
    a0 = max(-128, min(127, a0)); a1 = max(-128, min(127, a1));
    a2 = max(-128, min(127, a2)); a3 = max(-128, min(127, a3));
    unsigned p = (unsigned)(a0 & 255) | ((unsigned)(a1 & 255) << 8) |
                 ((unsigned)(a2 & 255) << 16) | ((unsigned)(a3 & 255) << 24);
    *(unsigned*)(k8 + (size_t)j * 4) = p;
    return;
  }
  int id = bx - 1024;
  int bh = id >> 4, b = bh >> 3, h = bh & 7;
  int j0 = (id & 15) * 64;
  const float s = 127.0f / __uint_as_float(scal[2]);
  int t = threadIdx.x;
  int j = t >> 2, dh0 = (t & 3) << 4;
  const float* src = kvf + (size_t)(b * MK + j0 + j) * 1024 + 512 + h * DH + dh0;
#pragma unroll
  for (int i = 0; i < 16; i += 4) {
    float4 v = *(const float4*)(src + i);
    int a0 = __float2int_rn(v.x * s), a1 = __float2int_rn(v.y * s);
    int a2 = __float2int_rn(v.z * s), a3 = __float2int_rn(v.w * s);
    tile[dh0 + i + 0][j] = (int8_t)max(-128, min(127, a0));
    tile[dh0 + i + 1][j] = (int8_t)max(-128, min(127, a1));
    tile[dh0 + i + 2][j] = (int8_t)max(-128, min(127, a2));
    tile[dh0 + i + 3][j] = (int8_t)max(-128, min(127, a3));
  }
  __syncthreads();
  int dh = t >> 2, jb = (t & 3) << 4;
  v4i val = *(const v4i*)(&tile[dh][jb]);
  *(v4i*)(v8t + (size_t)(bh * DH + dh) * MK + j0 + jb) = val;
}

__device__ __forceinline__ v4i quant_pack16(const float* p, float s) {
  v4i out;
#pragma unroll
  for (int q = 0; q < 4; ++q) {
    float4 v = *(const float4*)(p + q * 4);
    int a0 = __float2int_rn(v.x * s), a1 = __float2int_rn(v.y * s);
    int a2 = __float2int_rn(v.z * s), a3 = __float2int_rn(v.w * s);
    a0 = max(-128, min(127, a0)); a1 = max(-128, min(127, a1));
    a2 = max(-128, min(127, a2)); a3 = max(-128, min(127, a3));
    out[q] = (int)((unsigned)(a0 & 255) | ((unsigned)(a1 & 255) << 8) |
                   ((unsigned)(a2 & 255) << 16) | ((unsigned)(a3 & 255) << 24));
  }
  return out;
}

// pass 1: waves split q-rows (16 each); 8 tiles of 128 keys staged in LDS.
// z summation tree identical to prior rounds -> bit-identical invz.
__global__ __launch_bounds__(256, 4) void k_pass1(
    const float* __restrict__ qf, int8_t* __restrict__ q8,
    const int8_t* __restrict__ k8,
    float* __restrict__ invz, unsigned* __restrict__ scal) {
  __shared__ __align__(16) int8_t kbuf[128 * 72];
  __shared__ float mared[4];
  int bh = blockIdx.y, b = bh >> 3, h = bh & 7;
  int wave = threadIdx.x >> 6, lane = threadIdx.x & 63;
  int l15 = lane & 15, g = lane >> 4;
  int row0 = blockIdx.x * 64;
  int myrow = row0 + wave * 16 + l15;
  const float aq = __uint_as_float(scal[0]), ak = __uint_as_float(scal[1]);
  const float alpha2 = (aq * ak) * (0.125f / (127.0f * 127.0f)) * 1.44269504f;
  const float sq = 127.0f / aq;
  const v4i z4 = {0, 0, 0, 0};
  size_t qoff = (size_t)(b * NQ + myrow) * DMODEL + h * DH + g * 16;
  v4i qfrag = quant_pack16(qf + qoff, sq);
  *(v4i*)(q8 + qoff) = qfrag;
  const int8_t* kbase = k8 + (size_t)b * MK * DMODEL + h * DH;
  const int rs = threadIdx.x >> 2, qs = (threadIdx.x & 3) * 16;

  float z[4] = {0.f, 0.f, 0.f, 0.f};
  int mi = -(1 << 30);
  for (int tile = 0; tile < 8; ++tile) {
    __syncthreads();
    *(v4i*)(&kbuf[rs * 72 + qs]) =
        *(const v4i*)(kbase + (size_t)(tile * 128 + rs) * DMODEL + qs);
    *(v4i*)(&kbuf[(rs + 64) * 72 + qs]) =
        *(const v4i*)(kbase + (size_t)(tile * 128 + rs + 64) * DMODEL + qs);
    __syncthreads();
    float zt = z[tile >> 1];
#pragma unroll
    for (int t = 0; t < 8; ++t) {
      v4i kfrag = *(const v4i*)(&kbuf[(t * 16 + l15) * 72 + g * 16]);
      v4i sa = __builtin_amdgcn_mfma_i32_16x16x64_i8(kfrag, qfrag, z4, 0, 0, 0);
      mi = max(mi, max(max(sa[0], sa[1]), max(sa[2], sa[3])));
      float e0 = __builtin_amdgcn_exp2f((float)sa[0] * alpha2);
      float e1 = __builtin_amdgcn_exp2f((float)sa[1] * alpha2);
      float e2 = __builtin_amdgcn_exp2f((float)sa[2] * alpha2);
      float e3 = __builtin_amdgcn_exp2f((float)sa[3] * alpha2);
      zt += (e0 + e1) + (e2 + e3);
    }
    z[tile >> 1] = zt;
  }
#pragma unroll
  for (int i = 0; i < 4; ++i) {
    z[i] += __shfl_xor(z[i], 16, 64);
    z[i] += __shfl_xor(z[i], 32, 64);
  }
  mi = max(mi, __shfl_xor(mi, 16, 64));
  mi = max(mi, __shfl_xor(mi, 32, 64));
  float zt = (z[0] + z[1]) + (z[2] + z[3]);
  float iz = 1.0f / zt;
  if (g == 0) invz[(size_t)bh * NQ + myrow] = iz;
  float ma = __builtin_amdgcn_exp2f((float)mi * alpha2) * iz;  // row softmax max
#pragma unroll
  for (int off = 1; off < 16; off <<= 1)
    ma = fmaxf(ma, __shfl_xor(ma, off, 64));
  if (lane == 0) mared[wave] = ma;
  __syncthreads();
  if (threadIdx.x == 0)
    atomicMax(scal + 3,
              __float_as_uint(fmaxf(fmaxf(mared[0], mared[1]),
                                    fmaxf(mared[2], mared[3]))));
}

// pass 2: waves split q-rows; k/v tiles in block LDS; wave-private attn
// round-trip; exact int32 PV accumulation -> bit-identical output.
__global__ __launch_bounds__(256, 4) void k_pass2(
    const int8_t* __restrict__ q8, const int8_t* __restrict__ k8,
    const int8_t* __restrict__ v8t, const float* __restrict__ invz,
    const unsigned* __restrict__ scal, __bf16* __restrict__ o) {
  __shared__ __align__(16) int8_t kbuf[128 * 72];
  __shared__ __align__(16) int8_t vbuf[64 * 152];
  __shared__ __align__(16) int8_t albuf[4][16 * 152];
  int bh = blockIdx.y, b = bh >> 3, h = bh & 7;
  int wave = threadIdx.x >> 6, lane = threadIdx.x & 63;
  int l15 = lane & 15, g = lane >> 4;
  int row0 = blockIdx.x * 64;
  int myrow = row0 + wave * 16 + l15;
  const float aq = __uint_as_float(scal[0]), ak = __uint_as_float(scal[1]);
  const float avv = __uint_as_float(scal[2]), izm = __uint_as_float(scal[3]);
  const float alpha2 = (aq * ak) * (0.125f / (127.0f * 127.0f)) * 1.44269504f;
  const float oscale = (izm / 127.0f) * (avv / 127.0f);
  const float MAGIC = 12582912.0f;  // 1.5 * 2^23
  const v4i z4 = {0, 0, 0, 0};

  v4i qfrag = *(const v4i*)(q8 + (size_t)(b * NQ + myrow) * DMODEL + h * DH + g * 16);
  const float lcr = __builtin_amdgcn_logf(invz[(size_t)bh * NQ + myrow] * (127.0f / izm));
  const int8_t* kbase = k8 + (size_t)b * MK * DMODEL + h * DH;
  const int8_t* vbase = v8t + (size_t)bh * DH * MK;
  int8_t* alds = albuf[wave];
  const int rs = threadIdx.x >> 2, qs = (threadIdx.x & 3) * 16;
  const int vr = threadIdx.x >> 3, vq = (threadIdx.x & 7) * 16;

  v4i pacc[4] = {};
  for (int tile = 0; tile < 8; ++tile) {
    __syncthreads();
    *(v4i*)(&kbuf[rs * 72 + qs]) =
        *(const v4i*)(kbase + (size_t)(tile * 128 + rs) * DMODEL + qs);
    *(v4i*)(&kbuf[(rs + 64) * 72 + qs]) =
        *(const v4i*)(kbase + (size_t)(tile * 128 + rs + 64) * DMODEL + qs);
    *(v4i*)(&vbuf[vr * 152 + vq]) =
        *(const v4i*)(vbase + (size_t)vr * MK + tile * 128 + vq);
    *(v4i*)(&vbuf[(vr + 32) * 152 + vq]) =
        *(const v4i*)(vbase + (size_t)(vr + 32) * MK + tile * 128 + vq);
    __syncthreads();
#pragma unroll
    for (int t = 0; t < 8; ++t) {
      v4i kfrag = *(const v4i*)(&kbuf[(t * 16 + l15) * 72 + g * 16]);
      v4i sa = __builtin_amdgcn_mfma_i32_16x16x64_i8(kfrag, qfrag, z4, 0, 0, 0);
      float f0 = __builtin_amdgcn_exp2f(fmaf((float)sa[0], alpha2, lcr)) + MAGIC;
      float f1 = __builtin_amdgcn_exp2f(fmaf((float)sa[1], alpha2, lcr)) + MAGIC;
      float f2 = __builtin_amdgcn_exp2f(fmaf((float)sa[2], alpha2, lcr)) + MAGIC;
      float f3 = __builtin_amdgcn_exp2f(fmaf((float)sa[3], alpha2, lcr)) + MAGIC;
      unsigned packed = (__float_as_uint(f0) & 255u) |
                        ((__float_as_uint(f1) & 255u) << 8) |
                        ((__float_as_uint(f2) & 255u) << 16) |
                        (__float_as_uint(f3) << 24);
      *(unsigned*)(alds + l15 * 152 + t * 16 + g * 4) = packed;
    }
#pragma unroll
    for (int c = 0; c < 2; ++c) {
      v4i afrag = *(const v4i*)(alds + l15 * 152 + c * 64 + g * 16);
#pragma unroll
      for (int d = 0; d < 4; ++d) {
        v4i bfrag = *(const v4i*)(&vbuf[(d * 16 + l15) * 152 + c * 64 + g * 16]);
        pacc[d] = __builtin_amdgcn_mfma_i32_16x16x64_i8(afrag, bfrag, pacc[d], 0, 0, 0);
      }
    }
  }
  __bf16* obase = o + (size_t)(b * NQ + row0 + wave * 16) * DMODEL + h * DH;
#pragma unroll
  for (int d = 0; d < 4; ++d)
#pragma unroll
    for (int r = 0; r < 4; ++r)
      obase[(size_t)(g * 4 + r) * DMODEL + d * 16 + l15] =
          (__bf16)((float)pacc[d][r] * oscale);
}

extern "C" void kernel_launch(void* const* d_in, const int* in_sizes, int n_in,
                              void* d_out, int out_size, void* d_ws, size_t ws_size,
                              hipStream_t stream) {
  (void)in_sizes; (void)n_in; (void)out_size; (void)ws_size;
  const float* x   = (const float*)d_in[0];
  const float* ctx = (const float*)d_in[1];
  const float* Wq  = (const float*)d_in[2];
  const float* Wk  = (const float*)d_in[3];
  const float* Wv  = (const float*)d_in[4];
  const float* Wo  = (const float*)d_in[5];
  const float* bo  = (const float*)d_in[6];
  float* out = (float*)d_out;

  char* ws = (char*)d_ws;
  size_t off = 0;
  auto alloc = [&](size_t bytes) {
    char* p = ws + off;
    off += (bytes + 255) & ~(size_t)255;
    return p;
  };
  unsigned* scal = (unsigned*)alloc(16);
  __bf16* Wq_t = (__bf16*)alloc((size_t)512 * 512 * 2);
  __bf16* Wk_t = (__bf16*)alloc((size_t)512 * 768 * 2);  // contiguous with Wv_t
  __bf16* Wv_t = (__bf16*)alloc((size_t)512 * 768 * 2);
  __bf16* Wo_t = (__bf16*)alloc((size_t)512 * 512 * 2);
  __bf16* xb   = (__bf16*)alloc((size_t)BATCH * NQ * DMODEL * 2);
  __bf16* cb   = (__bf16*)alloc((size_t)BATCH * MK * DCTX * 2);
  float* qf  = (float*)alloc((size_t)BATCH * NQ * DMODEL * 4);   // later reused as o
  float* kvf = (float*)alloc((size_t)BATCH * MK * 1024 * 4);     // [2048][1024]: k | v
  int8_t* q8 = (int8_t*)alloc((size_t)BATCH * NQ * DMODEL);
  int8_t* k8 = (int8_t*)alloc((size_t)BATCH * MK * DMODEL);
  int8_t* v8t = (int8_t*)alloc((size_t)BATCH * NH * DH * MK);
  float* invz = (float*)alloc((size_t)BATCH * NH * NQ * 4);
  __bf16* o = (__bf16*)qf;  // q_f32 dead after pass1 quantizes it

  k_prep<<<4352, 256, 0, stream>>>(x, ctx, xb, cb, Wq, Wk, Wv, Wo,
                                   Wq_t, Wk_t, Wv_t, Wo_t, scal);
  k_gemm_qkv<<<1024, 256, 0, stream>>>(xb, Wq_t, qf, cb, Wk_t, kvf, scal);
  k_quant_kv<<<1280, 256, 0, stream>>>(kvf, k8, v8t, scal);
  k_pass1<<<dim3(64, 16), 256, 0, stream>>>(qf, q8, k8, invz, scal);
  k_pass2<<<dim3(64, 16), 256, 0, stream>>>(q8, k8, v8t, invz, scal, o);
  k_gemm_out<<<512, 256, 0, stream>>>(o, Wo_t, out, bo);
}